// Round 3
// baseline (176.759 us; speedup 1.0000x reference)
//
#include <hip/hip_runtime.h>
#include <hip/hip_bf16.h>

// GATConv on MI355X.
// Pipeline (2 kernels):
//   kA: blocks [0,512): x_l tile GEMM (bf16 MFMA) + fused transpose->xlT and
//       per-head alpha_l/alpha_r (alpha_l pre-scaled by log2e).
//       blocks [512,4608): pack adj (64MB int32) -> 2MB bitmask. Overlaps GEMM.
//   k3: block = (head, i-tile 32), 8 waves split j 8-ways.
//       P = bit ? exp2(al2*ar) : 0 built directly in MFMA A-frag layout;
//       acc += P @ x_l ; Z via MFMA with ones-B (same C/D row map -> no shuffle).
//       3-round LDS tree reduce, out = relu(acc * rcp(Z)) written directly.

#define NN    4096
#define NF    512
#define NH    8
#define CC    64
#define HC    512   // NH*CC
#define TI    32
#define GEMM_BLOCKS 512
#define PACK_BLOCKS 4096

typedef __bf16 bf16x8 __attribute__((ext_vector_type(8)));
typedef __bf16 bf16x4 __attribute__((ext_vector_type(4)));
typedef float  f32x4  __attribute__((ext_vector_type(4)));
typedef unsigned long long u64;

__device__ __forceinline__ float exp2_raw(float x) {
    float r;
    asm("v_exp_f32 %0, %1" : "=v"(r) : "v"(x));
    return r;
}

// ---------------- kA: fused pack + projection GEMM + transpose/alpha ----------------
__global__ __launch_bounds__(256) void kA(
    const int* __restrict__ adj, u64* __restrict__ bits,
    const float* __restrict__ X, const float* __restrict__ W,
    const float* __restrict__ bias, const float* __restrict__ attl,
    const float* __restrict__ attr, __bf16* __restrict__ xlT,
    float* __restrict__ alT, float* __restrict__ arT)
{
    const int tid = threadIdx.x;

    if (blockIdx.x >= GEMM_BLOCKS) {
        // ---- pack path: pure streaming, overlaps with GEMM blocks ----
        const int bid = blockIdx.x - GEMM_BLOCKS;
        const int stride = PACK_BLOCKS * 256;
        for (int t = bid * 256 + tid; t < NN * NN; t += stride) {
            u64 m = __ballot(adj[t] != 0);
            if ((tid & 63) == 0) bits[t >> 6] = m;
        }
        return;
    }

    // ---- GEMM path: one (64-row, 1-head) tile ----
    __shared__ __bf16 As[64][40];
    __shared__ __bf16 BsT[64][40];
    __shared__ __bf16 T[64][72];

    const int w  = tid >> 6;
    const int l  = tid & 63;
    const int lo = l & 15;
    const int hi = l >> 4;
    const int r0 = (blockIdx.x & 63) * 64;
    const int h  = blockIdx.x >> 6;
    const int c0 = h * CC;
    const int wm = (w >> 1) * 32;
    const int wn = (w & 1) * 32;

    f32x4 acc[2][2];
#pragma unroll
    for (int m = 0; m < 2; ++m)
#pragma unroll
        for (int n = 0; n < 2; ++n) acc[m][n] = (f32x4){0.f, 0.f, 0.f, 0.f};

    const int arow = tid >> 3;
    const int acol = (tid & 7) * 4;
    const int brow = tid >> 4;
    const int bcol = (tid & 15) * 4;

    for (int k0 = 0; k0 < NF; k0 += 32) {
        __syncthreads();
#pragma unroll
        for (int p = 0; p < 2; ++p) {
            int r = arow + p * 32;
            float4 v = *reinterpret_cast<const float4*>(&X[(r0 + r) * NF + k0 + acol]);
            bf16x4 av;
            av[0] = (__bf16)v.x; av[1] = (__bf16)v.y; av[2] = (__bf16)v.z; av[3] = (__bf16)v.w;
            *reinterpret_cast<bf16x4*>(&As[r][acol]) = av;
        }
#pragma unroll
        for (int p = 0; p < 2; ++p) {
            int kk = brow + p * 16;
            float4 v = *reinterpret_cast<const float4*>(&W[(k0 + kk) * HC + c0 + bcol]);
            BsT[bcol + 0][kk] = (__bf16)v.x;
            BsT[bcol + 1][kk] = (__bf16)v.y;
            BsT[bcol + 2][kk] = (__bf16)v.z;
            BsT[bcol + 3][kk] = (__bf16)v.w;
        }
        __syncthreads();

        bf16x8 a[2], b[2];
#pragma unroll
        for (int m = 0; m < 2; ++m)
            a[m] = *reinterpret_cast<const bf16x8*>(&As[wm + m * 16 + lo][hi * 8]);
#pragma unroll
        for (int n = 0; n < 2; ++n)
            b[n] = *reinterpret_cast<const bf16x8*>(&BsT[wn + n * 16 + lo][hi * 8]);
#pragma unroll
        for (int m = 0; m < 2; ++m)
#pragma unroll
            for (int n = 0; n < 2; ++n)
                acc[m][n] = __builtin_amdgcn_mfma_f32_16x16x32_bf16(a[m], b[n], acc[m][n], 0, 0, 0);
    }

    // epilogue: bias + bf16 round into LDS tile T (row-major)
    __syncthreads();
#pragma unroll
    for (int n = 0; n < 2; ++n) {
        const float bv = bias[c0 + wn + n * 16 + lo];
#pragma unroll
        for (int m = 0; m < 2; ++m)
#pragma unroll
            for (int r = 0; r < 4; ++r)
                T[wm + m * 16 + hi * 4 + r][wn + n * 16 + lo] = (__bf16)(acc[m][n][r] + bv);
    }
    __syncthreads();

    // transposed, coalesced store to xlT
    {
        const int cc_  = tid >> 3;
        const int row8 = (tid & 7) * 8;
#pragma unroll
        for (int p = 0; p < 2; ++p) {
            int cc = cc_ + p * 32;
            bf16x8 g;
#pragma unroll
            for (int j = 0; j < 8; ++j) g[j] = T[row8 + j][cc];
            *reinterpret_cast<bf16x8*>(&xlT[(c0 + cc) * NN + r0 + row8]) = g;
        }
    }
    // alpha_l (scaled by log2e) / alpha_r for these 64 rows
    {
        const int row = tid >> 2;
        const int q   = tid & 3;
        float pl = 0.f, pr = 0.f;
#pragma unroll
        for (int c = 0; c < 16; ++c) {
            const int cc = q * 16 + c;
            const float f = (float)T[row][cc];
            pl += f * attl[c0 + cc];
            pr += f * attr[c0 + cc];
        }
        pl += __shfl_xor(pl, 1); pl += __shfl_xor(pl, 2);
        pr += __shfl_xor(pr, 1); pr += __shfl_xor(pr, 2);
        if (q == 0) {
            alT[h * NN + r0 + row] = pl * 1.4426950408889634f;
            arT[h * NN + r0 + row] = pr;
        }
    }
}

// ---------------- k3: fused mask+exp+aggregate+Z+normalize+ReLU ----------------
__global__ __launch_bounds__(512, 6) void k3_attn(
    const u64* __restrict__ abits, const __bf16* __restrict__ xlT,
    const float* __restrict__ alT, const float* __restrict__ arT,
    float* __restrict__ out)
{
    __shared__ float rA[4][64][41];   // tree-reduction buffers (40 payload + pad)

    const int tid = threadIdx.x;
    const int wv  = tid >> 6;        // wave 0..7 : j-split
    const int l   = tid & 63;
    const int lo  = l & 15;
    const int hi  = l >> 4;
    const int h   = blockIdx.x;      // head
    const int i0  = blockIdx.y * TI; // i-tile

    const float al20 = alT[h * NN + i0 + lo];
    const float al21 = alT[h * NN + i0 + 16 + lo];

    f32x4 acc[2][4];
    f32x4 accz[2];
#pragma unroll
    for (int m = 0; m < 2; ++m) {
        accz[m] = (f32x4){0.f, 0.f, 0.f, 0.f};
#pragma unroll
        for (int n = 0; n < 4; ++n) acc[m][n] = (f32x4){0.f, 0.f, 0.f, 0.f};
    }
    bf16x8 ones;
#pragma unroll
    for (int j = 0; j < 8; ++j) ones[j] = (__bf16)1.0f;

    const u64* ab0p = &abits[(i0 + lo) * (NN / 64)];
    const u64* ab1p = &abits[(i0 + 16 + lo) * (NN / 64)];
    const int w0 = wv * 8;

    for (int it = 0; it < 8; ++it) {
        const u64 ab0 = ab0p[w0 + it];
        const u64 ab1 = ab1p[w0 + it];
        const int j0 = wv * 512 + it * 64;
#pragma unroll
        for (int s = 0; s < 2; ++s) {
            const int jj = j0 + s * 32 + hi * 8;
            const float* rp = &arT[h * NN + jj];
            f32x4 rv0 = *reinterpret_cast<const f32x4*>(rp);
            f32x4 rv1 = *reinterpret_cast<const f32x4*>(rp + 4);
            bf16x8 bX[4];
#pragma unroll
            for (int n = 0; n < 4; ++n)
                bX[n] = *reinterpret_cast<const bf16x8*>(&xlT[(h * CC + n * 16 + lo) * NN + jj]);
            const int sh = s * 32 + hi * 8;
#pragma unroll
            for (int m = 0; m < 2; ++m) {
                const unsigned int byte = (unsigned int)(((m ? ab1 : ab0) >> sh) & 0xffULL);
                const float alm = m ? al21 : al20;
                float p0 = (byte & 1u)   ? exp2_raw(alm * rv0[0]) : 0.f;
                float p1 = (byte & 2u)   ? exp2_raw(alm * rv0[1]) : 0.f;
                float p2 = (byte & 4u)   ? exp2_raw(alm * rv0[2]) : 0.f;
                float p3 = (byte & 8u)   ? exp2_raw(alm * rv0[3]) : 0.f;
                float p4 = (byte & 16u)  ? exp2_raw(alm * rv1[0]) : 0.f;
                float p5 = (byte & 32u)  ? exp2_raw(alm * rv1[1]) : 0.f;
                float p6 = (byte & 64u)  ? exp2_raw(alm * rv1[2]) : 0.f;
                float p7 = (byte & 128u) ? exp2_raw(alm * rv1[3]) : 0.f;
                bf16x8 aP;
                aP[0] = (__bf16)p0; aP[1] = (__bf16)p1; aP[2] = (__bf16)p2; aP[3] = (__bf16)p3;
                aP[4] = (__bf16)p4; aP[5] = (__bf16)p5; aP[6] = (__bf16)p6; aP[7] = (__bf16)p7;
                accz[m] = __builtin_amdgcn_mfma_f32_16x16x32_bf16(aP, ones, accz[m], 0, 0, 0);
#pragma unroll
                for (int n = 0; n < 4; ++n)
                    acc[m][n] = __builtin_amdgcn_mfma_f32_16x16x32_bf16(aP, bX[n], acc[m][n], 0, 0, 0);
            }
        }
    }

    // ---- 3-round LDS tree reduce across 8 waves (payload: 32 acc + 8 z) ----
    if (wv >= 4) {
#pragma unroll
        for (int m = 0; m < 2; ++m) {
#pragma unroll
            for (int n = 0; n < 4; ++n)
#pragma unroll
                for (int r = 0; r < 4; ++r)
                    rA[wv - 4][l][m * 16 + n * 4 + r] = acc[m][n][r];
#pragma unroll
            for (int r = 0; r < 4; ++r)
                rA[wv - 4][l][32 + m * 4 + r] = accz[m][r];
        }
    }
    __syncthreads();
    if (wv < 4) {
#pragma unroll
        for (int m = 0; m < 2; ++m) {
#pragma unroll
            for (int n = 0; n < 4; ++n)
#pragma unroll
                for (int r = 0; r < 4; ++r)
                    acc[m][n][r] += rA[wv][l][m * 16 + n * 4 + r];
#pragma unroll
            for (int r = 0; r < 4; ++r)
                accz[m][r] += rA[wv][l][32 + m * 4 + r];
        }
    }
    __syncthreads();
    if (wv >= 2 && wv < 4) {
#pragma unroll
        for (int m = 0; m < 2; ++m) {
#pragma unroll
            for (int n = 0; n < 4; ++n)
#pragma unroll
                for (int r = 0; r < 4; ++r)
                    rA[wv - 2][l][m * 16 + n * 4 + r] = acc[m][n][r];
#pragma unroll
            for (int r = 0; r < 4; ++r)
                rA[wv - 2][l][32 + m * 4 + r] = accz[m][r];
        }
    }
    __syncthreads();
    if (wv < 2) {
#pragma unroll
        for (int m = 0; m < 2; ++m) {
#pragma unroll
            for (int n = 0; n < 4; ++n)
#pragma unroll
                for (int r = 0; r < 4; ++r)
                    acc[m][n][r] += rA[wv][l][m * 16 + n * 4 + r];
#pragma unroll
            for (int r = 0; r < 4; ++r)
                accz[m][r] += rA[wv][l][32 + m * 4 + r];
        }
    }
    __syncthreads();
    if (wv == 1) {
#pragma unroll
        for (int m = 0; m < 2; ++m) {
#pragma unroll
            for (int n = 0; n < 4; ++n)
#pragma unroll
                for (int r = 0; r < 4; ++r)
                    rA[0][l][m * 16 + n * 4 + r] = acc[m][n][r];
#pragma unroll
            for (int r = 0; r < 4; ++r)
                rA[0][l][32 + m * 4 + r] = accz[m][r];
        }
    }
    __syncthreads();
    if (wv == 0) {
#pragma unroll
        for (int m = 0; m < 2; ++m) {
#pragma unroll
            for (int r = 0; r < 4; ++r) {
                const float zf = accz[m][r] + rA[0][l][32 + m * 4 + r];
                const float zr = __builtin_amdgcn_rcpf(zf);
                const int row = i0 + m * 16 + hi * 4 + r;
#pragma unroll
                for (int n = 0; n < 4; ++n) {
                    const float o = (acc[m][n][r] + rA[0][l][m * 16 + n * 4 + r]) * zr;
                    out[row * HC + h * CC + n * 16 + lo] = o > 0.f ? o : 0.f;
                }
            }
        }
    }
}

extern "C" void kernel_launch(void* const* d_in, const int* in_sizes, int n_in,
                              void* d_out, int out_size, void* d_ws, size_t ws_size,
                              hipStream_t stream)
{
    const float* x    = (const float*)d_in[0];
    const int*   adj  = (const int*)d_in[1];
    const float* W    = (const float*)d_in[2];
    const float* bias = (const float*)d_in[3];
    const float* attl = (const float*)d_in[4];
    const float* attr = (const float*)d_in[5];
    float* out = (float*)d_out;

    char* ws = (char*)d_ws;
    __bf16* xlT  = (__bf16*)(ws);                               // 4 MB
    float*  alT  = (float*)(ws + (4u << 20));                   // 128 KB
    float*  arT  = (float*)(ws + (4u << 20) + (128u << 10));    // 128 KB
    u64*    abit = (u64*)(ws + (4u << 20) + (256u << 10));      // 2 MB

    kA<<<dim3(GEMM_BLOCKS + PACK_BLOCKS), 256, 0, stream>>>(
        adj, abit, x, W, bias, attl, attr, xlT, alT, arT);
    k3_attn<<<dim3(NH, NN / TI), 512, 0, stream>>>(abit, xlT, alT, arT, out);
}

// Round 4
// 116.901 us; speedup vs baseline: 1.5120x; 1.5120x over previous
//
#include <hip/hip_runtime.h>
#include <hip/hip_bf16.h>

// GATConv on MI355X.
// Pipeline (2 kernels):
//   kA: blocks [0,512): x_l tile GEMM (bf16 MFMA) + fused transpose->xlT and
//       per-head alpha_l/alpha_r (alpha_l pre-scaled by log2e).
//       blocks [512,4608): pack adj (64MB int32) -> 2MB bitmask. Overlaps GEMM.
//   k3: block = (head, i-tile 64), 8 waves = 2 i-halves x 4 j-quarters.
//       P = bit ? exp2(al2*ar) : 0 built directly in MFMA A-frag layout;
//       acc += P @ x_l ; Z via MFMA with ones-B (same C/D row map).
//       Per i-half 2-round LDS tree reduce (2 phases to keep LDS at 21.5KB),
//       out = relu(acc * rcp(Z)) written directly.
//   grid.x = 8 heads = 8 XCDs -> round-robin dispatch gives per-head L2 locality.

#define NN    4096
#define NF    512
#define NH    8
#define CC    64
#define HC    512   // NH*CC
#define GEMM_BLOCKS 512
#define PACK_BLOCKS 4096

typedef __bf16 bf16x8 __attribute__((ext_vector_type(8)));
typedef __bf16 bf16x4 __attribute__((ext_vector_type(4)));
typedef float  f32x4  __attribute__((ext_vector_type(4)));
typedef unsigned long long u64;

__device__ __forceinline__ float exp2_raw(float x) {
    float r;
    asm("v_exp_f32 %0, %1" : "=v"(r) : "v"(x));
    return r;
}

// ---------------- kA: fused pack + projection GEMM + transpose/alpha ----------------
__global__ __launch_bounds__(256) void kA(
    const int* __restrict__ adj, u64* __restrict__ bits,
    const float* __restrict__ X, const float* __restrict__ W,
    const float* __restrict__ bias, const float* __restrict__ attl,
    const float* __restrict__ attr, __bf16* __restrict__ xlT,
    float* __restrict__ alT, float* __restrict__ arT)
{
    const int tid = threadIdx.x;

    if (blockIdx.x >= GEMM_BLOCKS) {
        // ---- pack path: pure streaming, overlaps with GEMM blocks ----
        const int bid = blockIdx.x - GEMM_BLOCKS;
        const int stride = PACK_BLOCKS * 256;
        for (int t = bid * 256 + tid; t < NN * NN; t += stride) {
            u64 m = __ballot(adj[t] != 0);
            if ((tid & 63) == 0) bits[t >> 6] = m;
        }
        return;
    }

    // ---- GEMM path: one (64-row, 1-head) tile ----
    __shared__ __bf16 As[64][40];
    __shared__ __bf16 BsT[64][40];
    __shared__ __bf16 T[64][72];

    const int w  = tid >> 6;
    const int l  = tid & 63;
    const int lo = l & 15;
    const int hi = l >> 4;
    const int r0 = (blockIdx.x & 63) * 64;
    const int h  = blockIdx.x >> 6;
    const int c0 = h * CC;
    const int wm = (w >> 1) * 32;
    const int wn = (w & 1) * 32;

    f32x4 acc[2][2];
#pragma unroll
    for (int m = 0; m < 2; ++m)
#pragma unroll
        for (int n = 0; n < 2; ++n) acc[m][n] = (f32x4){0.f, 0.f, 0.f, 0.f};

    const int arow = tid >> 3;
    const int acol = (tid & 7) * 4;
    const int brow = tid >> 4;
    const int bcol = (tid & 15) * 4;

    for (int k0 = 0; k0 < NF; k0 += 32) {
        __syncthreads();
#pragma unroll
        for (int p = 0; p < 2; ++p) {
            int r = arow + p * 32;
            float4 v = *reinterpret_cast<const float4*>(&X[(r0 + r) * NF + k0 + acol]);
            bf16x4 av;
            av[0] = (__bf16)v.x; av[1] = (__bf16)v.y; av[2] = (__bf16)v.z; av[3] = (__bf16)v.w;
            *reinterpret_cast<bf16x4*>(&As[r][acol]) = av;
        }
#pragma unroll
        for (int p = 0; p < 2; ++p) {
            int kk = brow + p * 16;
            float4 v = *reinterpret_cast<const float4*>(&W[(k0 + kk) * HC + c0 + bcol]);
            BsT[bcol + 0][kk] = (__bf16)v.x;
            BsT[bcol + 1][kk] = (__bf16)v.y;
            BsT[bcol + 2][kk] = (__bf16)v.z;
            BsT[bcol + 3][kk] = (__bf16)v.w;
        }
        __syncthreads();

        bf16x8 a[2], b[2];
#pragma unroll
        for (int m = 0; m < 2; ++m)
            a[m] = *reinterpret_cast<const bf16x8*>(&As[wm + m * 16 + lo][hi * 8]);
#pragma unroll
        for (int n = 0; n < 2; ++n)
            b[n] = *reinterpret_cast<const bf16x8*>(&BsT[wn + n * 16 + lo][hi * 8]);
#pragma unroll
        for (int m = 0; m < 2; ++m)
#pragma unroll
            for (int n = 0; n < 2; ++n)
                acc[m][n] = __builtin_amdgcn_mfma_f32_16x16x32_bf16(a[m], b[n], acc[m][n], 0, 0, 0);
    }

    // epilogue: bias + bf16 round into LDS tile T (row-major)
    __syncthreads();
#pragma unroll
    for (int n = 0; n < 2; ++n) {
        const float bv = bias[c0 + wn + n * 16 + lo];
#pragma unroll
        for (int m = 0; m < 2; ++m)
#pragma unroll
            for (int r = 0; r < 4; ++r)
                T[wm + m * 16 + hi * 4 + r][wn + n * 16 + lo] = (__bf16)(acc[m][n][r] + bv);
    }
    __syncthreads();

    // transposed, coalesced store to xlT
    {
        const int cc_  = tid >> 3;
        const int row8 = (tid & 7) * 8;
#pragma unroll
        for (int p = 0; p < 2; ++p) {
            int cc = cc_ + p * 32;
            bf16x8 g;
#pragma unroll
            for (int j = 0; j < 8; ++j) g[j] = T[row8 + j][cc];
            *reinterpret_cast<bf16x8*>(&xlT[(c0 + cc) * NN + r0 + row8]) = g;
        }
    }
    // alpha_l (scaled by log2e) / alpha_r for these 64 rows
    {
        const int row = tid >> 2;
        const int q   = tid & 3;
        float pl = 0.f, pr = 0.f;
#pragma unroll
        for (int c = 0; c < 16; ++c) {
            const int cc = q * 16 + c;
            const float f = (float)T[row][cc];
            pl += f * attl[c0 + cc];
            pr += f * attr[c0 + cc];
        }
        pl += __shfl_xor(pl, 1); pl += __shfl_xor(pl, 2);
        pr += __shfl_xor(pr, 1); pr += __shfl_xor(pr, 2);
        if (q == 0) {
            alT[h * NN + r0 + row] = pl * 1.4426950408889634f;
            arT[h * NN + r0 + row] = pr;
        }
    }
}

// ---------------- k3: fused mask+exp+aggregate+Z+normalize+ReLU ----------------
__global__ __launch_bounds__(512, 4) void k3_attn(
    const u64* __restrict__ abits, const __bf16* __restrict__ xlT,
    const float* __restrict__ alT, const float* __restrict__ arT,
    float* __restrict__ out)
{
    // per i-half (ig) reduction buffers; 2 phases (m=0,1), payload 20 floats
    __shared__ float rb[2][2][64][21];   // [ig][slot][lane][payload+pad] = 21.5 KB

    const int tid = threadIdx.x;
    const int wv  = tid >> 6;        // 8 waves
    const int ig  = wv >> 2;         // i-half 0/1
    const int jq  = wv & 3;          // j-quarter 0..3
    const int l   = tid & 63;
    const int lo  = l & 15;
    const int hi  = l >> 4;
    const int h   = blockIdx.x;      // head (== XCD via round-robin dispatch)
    const int i0  = blockIdx.y * 64 + ig * 32;

    const float al20 = alT[h * NN + i0 + lo];
    const float al21 = alT[h * NN + i0 + 16 + lo];

    f32x4 acc[2][4];
    f32x4 accz[2];
#pragma unroll
    for (int m = 0; m < 2; ++m) {
        accz[m] = (f32x4){0.f, 0.f, 0.f, 0.f};
#pragma unroll
        for (int n = 0; n < 4; ++n) acc[m][n] = (f32x4){0.f, 0.f, 0.f, 0.f};
    }
    bf16x8 ones;
#pragma unroll
    for (int j = 0; j < 8; ++j) ones[j] = (__bf16)1.0f;

    const u64* ab0p = &abits[(i0 + lo) * (NN / 64)];
    const u64* ab1p = &abits[(i0 + 16 + lo) * (NN / 64)];
    const float* arp = &arT[h * NN];
    const __bf16* xp = &xlT[(h * CC) * NN];
    const int w0 = jq * 16;          // 16 u64 words per quarter (1024 j)

    for (int it = 0; it < 16; ++it) {
        const u64 ab0 = ab0p[w0 + it];
        const u64 ab1 = ab1p[w0 + it];
        const int j0 = (w0 + it) * 64;
#pragma unroll
        for (int s = 0; s < 2; ++s) {
            const int jj = j0 + s * 32 + hi * 8;
            f32x4 rv0 = *reinterpret_cast<const f32x4*>(arp + jj);
            f32x4 rv1 = *reinterpret_cast<const f32x4*>(arp + jj + 4);
            bf16x8 bX[4];
#pragma unroll
            for (int n = 0; n < 4; ++n)
                bX[n] = *reinterpret_cast<const bf16x8*>(&xp[(n * 16 + lo) * NN + jj]);
            const int sh = s * 32 + hi * 8;
#pragma unroll
            for (int m = 0; m < 2; ++m) {
                const unsigned int byte = (unsigned int)(((m ? ab1 : ab0) >> sh) & 0xffULL);
                const float alm = m ? al21 : al20;
                float p0 = (byte & 1u)   ? exp2_raw(alm * rv0[0]) : 0.f;
                float p1 = (byte & 2u)   ? exp2_raw(alm * rv0[1]) : 0.f;
                float p2 = (byte & 4u)   ? exp2_raw(alm * rv0[2]) : 0.f;
                float p3 = (byte & 8u)   ? exp2_raw(alm * rv0[3]) : 0.f;
                float p4 = (byte & 16u)  ? exp2_raw(alm * rv1[0]) : 0.f;
                float p5 = (byte & 32u)  ? exp2_raw(alm * rv1[1]) : 0.f;
                float p6 = (byte & 64u)  ? exp2_raw(alm * rv1[2]) : 0.f;
                float p7 = (byte & 128u) ? exp2_raw(alm * rv1[3]) : 0.f;
                bf16x8 aP;
                aP[0] = (__bf16)p0; aP[1] = (__bf16)p1; aP[2] = (__bf16)p2; aP[3] = (__bf16)p3;
                aP[4] = (__bf16)p4; aP[5] = (__bf16)p5; aP[6] = (__bf16)p6; aP[7] = (__bf16)p7;
                accz[m] = __builtin_amdgcn_mfma_f32_16x16x32_bf16(aP, ones, accz[m], 0, 0, 0);
#pragma unroll
                for (int n = 0; n < 4; ++n)
                    acc[m][n] = __builtin_amdgcn_mfma_f32_16x16x32_bf16(aP, bX[n], acc[m][n], 0, 0, 0);
            }
        }
    }

    // ---- per i-half 2-round tree reduce over j-quarters, 2 phases (m) ----
#pragma unroll
    for (int m = 0; m < 2; ++m) {
        if (jq >= 2) {
#pragma unroll
            for (int n = 0; n < 4; ++n)
#pragma unroll
                for (int r = 0; r < 4; ++r)
                    rb[ig][jq - 2][l][n * 4 + r] = acc[m][n][r];
#pragma unroll
            for (int r = 0; r < 4; ++r)
                rb[ig][jq - 2][l][16 + r] = accz[m][r];
        }
        __syncthreads();
        if (jq < 2) {
#pragma unroll
            for (int n = 0; n < 4; ++n)
#pragma unroll
                for (int r = 0; r < 4; ++r)
                    acc[m][n][r] += rb[ig][jq][l][n * 4 + r];
#pragma unroll
            for (int r = 0; r < 4; ++r)
                accz[m][r] += rb[ig][jq][l][16 + r];
        }
        __syncthreads();
        if (jq == 1) {
#pragma unroll
            for (int n = 0; n < 4; ++n)
#pragma unroll
                for (int r = 0; r < 4; ++r)
                    rb[ig][0][l][n * 4 + r] = acc[m][n][r];
#pragma unroll
            for (int r = 0; r < 4; ++r)
                rb[ig][0][l][16 + r] = accz[m][r];
        }
        __syncthreads();
        if (jq == 0) {
#pragma unroll
            for (int r = 0; r < 4; ++r) {
                const float zf = accz[m][r] + rb[ig][0][l][16 + r];
                const float zr = __builtin_amdgcn_rcpf(zf);
                const int row = i0 + m * 16 + hi * 4 + r;
#pragma unroll
                for (int n = 0; n < 4; ++n) {
                    const float o = (acc[m][n][r] + rb[ig][0][l][n * 4 + r]) * zr;
                    out[row * HC + h * CC + n * 16 + lo] = o > 0.f ? o : 0.f;
                }
            }
        }
        if (m == 0) __syncthreads();   // protect buffer reuse for phase 1
    }
}

extern "C" void kernel_launch(void* const* d_in, const int* in_sizes, int n_in,
                              void* d_out, int out_size, void* d_ws, size_t ws_size,
                              hipStream_t stream)
{
    const float* x    = (const float*)d_in[0];
    const int*   adj  = (const int*)d_in[1];
    const float* W    = (const float*)d_in[2];
    const float* bias = (const float*)d_in[3];
    const float* attl = (const float*)d_in[4];
    const float* attr = (const float*)d_in[5];
    float* out = (float*)d_out;

    char* ws = (char*)d_ws;
    __bf16* xlT  = (__bf16*)(ws);                               // 4 MB
    float*  alT  = (float*)(ws + (4u << 20));                   // 128 KB
    float*  arT  = (float*)(ws + (4u << 20) + (128u << 10));    // 128 KB
    u64*    abit = (u64*)(ws + (4u << 20) + (256u << 10));      // 2 MB

    kA<<<dim3(GEMM_BLOCKS + PACK_BLOCKS), 256, 0, stream>>>(
        adj, abit, x, W, bias, attl, attr, xlT, alT, arT);
    k3_attn<<<dim3(NH, NN / 64), 512, 0, stream>>>(abit, xlT, alT, arT, out);
}

// Round 5
// 116.263 us; speedup vs baseline: 1.5203x; 1.0055x over previous
//
#include <hip/hip_runtime.h>
#include <hip/hip_bf16.h>

// GATConv on MI355X.
// Pipeline (2 kernels):
//   kA: blocks [0,512): x_l tile GEMM (bf16 MFMA) + fused transpose->xlT and
//       per-head alpha_l/alpha_r (alpha_l pre-scaled by log2e).
//       blocks [512,4608): pack adj (64MB int32) -> 2MB bitmask. Overlaps GEMM.
//   k3: block = (head, i-tile 32), 8 waves = 8 j-eighths (512 j each).
//       grid 1024 = 4 blocks/CU -> 32 waves/CU (100% static occupancy).
//       P = bit ? exp2(al2*ar) : 0 (branchless: exp computed, cndmask-selected),
//       built directly in MFMA A-frag layout; acc += P @ x_l ; Z via MFMA ones-B.
//       2-phase x 3-round LDS tree reduce (21.5 KB), out = relu(acc*rcp(Z)).
//   grid.x = 8 heads = 8 XCDs -> round-robin dispatch gives per-head L2 locality.

#define NN    4096
#define NF    512
#define NH    8
#define CC    64
#define HC    512   // NH*CC
#define GEMM_BLOCKS 512
#define PACK_BLOCKS 4096

typedef __bf16 bf16x8 __attribute__((ext_vector_type(8)));
typedef __bf16 bf16x4 __attribute__((ext_vector_type(4)));
typedef float  f32x4  __attribute__((ext_vector_type(4)));
typedef unsigned long long u64;

__device__ __forceinline__ float exp2_raw(float x) {
    float r;
    asm("v_exp_f32 %0, %1" : "=v"(r) : "v"(x));
    return r;
}

// ---------------- kA: fused pack + projection GEMM + transpose/alpha ----------------
__global__ __launch_bounds__(256) void kA(
    const int* __restrict__ adj, u64* __restrict__ bits,
    const float* __restrict__ X, const float* __restrict__ W,
    const float* __restrict__ bias, const float* __restrict__ attl,
    const float* __restrict__ attr, __bf16* __restrict__ xlT,
    float* __restrict__ alT, float* __restrict__ arT)
{
    const int tid = threadIdx.x;

    if (blockIdx.x >= GEMM_BLOCKS) {
        // ---- pack path: pure streaming, overlaps with GEMM blocks ----
        const int bid = blockIdx.x - GEMM_BLOCKS;
        const int stride = PACK_BLOCKS * 256;
        for (int t = bid * 256 + tid; t < NN * NN; t += stride) {
            u64 m = __ballot(adj[t] != 0);
            if ((tid & 63) == 0) bits[t >> 6] = m;
        }
        return;
    }

    // ---- GEMM path: one (64-row, 1-head) tile ----
    __shared__ __bf16 As[64][40];
    __shared__ __bf16 BsT[64][40];
    __shared__ __bf16 T[64][72];

    const int w  = tid >> 6;
    const int l  = tid & 63;
    const int lo = l & 15;
    const int hi = l >> 4;
    const int r0 = (blockIdx.x & 63) * 64;
    const int h  = blockIdx.x >> 6;
    const int c0 = h * CC;
    const int wm = (w >> 1) * 32;
    const int wn = (w & 1) * 32;

    f32x4 acc[2][2];
#pragma unroll
    for (int m = 0; m < 2; ++m)
#pragma unroll
        for (int n = 0; n < 2; ++n) acc[m][n] = (f32x4){0.f, 0.f, 0.f, 0.f};

    const int arow = tid >> 3;
    const int acol = (tid & 7) * 4;
    const int brow = tid >> 4;
    const int bcol = (tid & 15) * 4;

    for (int k0 = 0; k0 < NF; k0 += 32) {
        __syncthreads();
#pragma unroll
        for (int p = 0; p < 2; ++p) {
            int r = arow + p * 32;
            float4 v = *reinterpret_cast<const float4*>(&X[(r0 + r) * NF + k0 + acol]);
            bf16x4 av;
            av[0] = (__bf16)v.x; av[1] = (__bf16)v.y; av[2] = (__bf16)v.z; av[3] = (__bf16)v.w;
            *reinterpret_cast<bf16x4*>(&As[r][acol]) = av;
        }
#pragma unroll
        for (int p = 0; p < 2; ++p) {
            int kk = brow + p * 16;
            float4 v = *reinterpret_cast<const float4*>(&W[(k0 + kk) * HC + c0 + bcol]);
            BsT[bcol + 0][kk] = (__bf16)v.x;
            BsT[bcol + 1][kk] = (__bf16)v.y;
            BsT[bcol + 2][kk] = (__bf16)v.z;
            BsT[bcol + 3][kk] = (__bf16)v.w;
        }
        __syncthreads();

        bf16x8 a[2], b[2];
#pragma unroll
        for (int m = 0; m < 2; ++m)
            a[m] = *reinterpret_cast<const bf16x8*>(&As[wm + m * 16 + lo][hi * 8]);
#pragma unroll
        for (int n = 0; n < 2; ++n)
            b[n] = *reinterpret_cast<const bf16x8*>(&BsT[wn + n * 16 + lo][hi * 8]);
#pragma unroll
        for (int m = 0; m < 2; ++m)
#pragma unroll
            for (int n = 0; n < 2; ++n)
                acc[m][n] = __builtin_amdgcn_mfma_f32_16x16x32_bf16(a[m], b[n], acc[m][n], 0, 0, 0);
    }

    // epilogue: bias + bf16 round into LDS tile T (row-major)
    __syncthreads();
#pragma unroll
    for (int n = 0; n < 2; ++n) {
        const float bv = bias[c0 + wn + n * 16 + lo];
#pragma unroll
        for (int m = 0; m < 2; ++m)
#pragma unroll
            for (int r = 0; r < 4; ++r)
                T[wm + m * 16 + hi * 4 + r][wn + n * 16 + lo] = (__bf16)(acc[m][n][r] + bv);
    }
    __syncthreads();

    // transposed, coalesced store to xlT
    {
        const int cc_  = tid >> 3;
        const int row8 = (tid & 7) * 8;
#pragma unroll
        for (int p = 0; p < 2; ++p) {
            int cc = cc_ + p * 32;
            bf16x8 g;
#pragma unroll
            for (int j = 0; j < 8; ++j) g[j] = T[row8 + j][cc];
            *reinterpret_cast<bf16x8*>(&xlT[(c0 + cc) * NN + r0 + row8]) = g;
        }
    }
    // alpha_l (scaled by log2e) / alpha_r for these 64 rows
    {
        const int row = tid >> 2;
        const int q   = tid & 3;
        float pl = 0.f, pr = 0.f;
#pragma unroll
        for (int c = 0; c < 16; ++c) {
            const int cc = q * 16 + c;
            const float f = (float)T[row][cc];
            pl += f * attl[c0 + cc];
            pr += f * attr[c0 + cc];
        }
        pl += __shfl_xor(pl, 1); pl += __shfl_xor(pl, 2);
        pr += __shfl_xor(pr, 1); pr += __shfl_xor(pr, 2);
        if (q == 0) {
            alT[h * NN + r0 + row] = pl * 1.4426950408889634f;
            arT[h * NN + r0 + row] = pr;
        }
    }
}

// ---------------- k3: fused mask+exp+aggregate+Z+normalize+ReLU ----------------
__global__ __launch_bounds__(512, 4) void k3_attn(
    const u64* __restrict__ abits, const __bf16* __restrict__ xlT,
    const float* __restrict__ alT, const float* __restrict__ arT,
    float* __restrict__ out)
{
    // 2 phases (m=0,1), 3-round tree over 8 waves; payload 20 floats
    __shared__ float rb[4][64][21];   // [slot][lane][payload+pad] = 21.5 KB

    const int tid = threadIdx.x;
    const int wv  = tid >> 6;        // 8 waves : j-eighths
    const int l   = tid & 63;
    const int lo  = l & 15;
    const int hi  = l >> 4;
    const int h   = blockIdx.x;      // head (== XCD via round-robin dispatch)
    const int i0  = blockIdx.y * 32;

    const float al20 = alT[h * NN + i0 + lo];
    const float al21 = alT[h * NN + i0 + 16 + lo];

    f32x4 acc[2][4];
    f32x4 accz[2];
#pragma unroll
    for (int m = 0; m < 2; ++m) {
        accz[m] = (f32x4){0.f, 0.f, 0.f, 0.f};
#pragma unroll
        for (int n = 0; n < 4; ++n) acc[m][n] = (f32x4){0.f, 0.f, 0.f, 0.f};
    }
    bf16x8 ones;
#pragma unroll
    for (int j = 0; j < 8; ++j) ones[j] = (__bf16)1.0f;

    const u64* ab0p = &abits[(i0 + lo) * (NN / 64)];
    const u64* ab1p = &abits[(i0 + 16 + lo) * (NN / 64)];
    const float* arp = &arT[h * NN];
    const __bf16* xp = &xlT[(h * CC) * NN];
    const int w0 = wv * 8;           // 8 u64 words per eighth (512 j)

    for (int it = 0; it < 8; ++it) {
        const u64 ab0 = ab0p[w0 + it];
        const u64 ab1 = ab1p[w0 + it];
        const int j0 = (w0 + it) * 64;
#pragma unroll
        for (int s = 0; s < 2; ++s) {
            const int jj = j0 + s * 32 + hi * 8;
            f32x4 rv0 = *reinterpret_cast<const f32x4*>(arp + jj);
            f32x4 rv1 = *reinterpret_cast<const f32x4*>(arp + jj + 4);
            bf16x8 bX[4];
#pragma unroll
            for (int n = 0; n < 4; ++n)
                bX[n] = *reinterpret_cast<const bf16x8*>(&xp[(n * 16 + lo) * NN + jj]);
            const int sh = s * 32 + hi * 8;
#pragma unroll
            for (int m = 0; m < 2; ++m) {
                const unsigned int byte = (unsigned int)(((m ? ab1 : ab0) >> sh) & 0xffULL);
                const float alm = m ? al21 : al20;
                // branchless: exp always computed, cndmask-selected (no divergent
                // branches around inline asm)
                const float e0 = exp2_raw(alm * rv0[0]);
                const float e1 = exp2_raw(alm * rv0[1]);
                const float e2 = exp2_raw(alm * rv0[2]);
                const float e3 = exp2_raw(alm * rv0[3]);
                const float e4 = exp2_raw(alm * rv1[0]);
                const float e5 = exp2_raw(alm * rv1[1]);
                const float e6 = exp2_raw(alm * rv1[2]);
                const float e7 = exp2_raw(alm * rv1[3]);
                const float p0 = (byte & 1u)   ? e0 : 0.f;
                const float p1 = (byte & 2u)   ? e1 : 0.f;
                const float p2 = (byte & 4u)   ? e2 : 0.f;
                const float p3 = (byte & 8u)   ? e3 : 0.f;
                const float p4 = (byte & 16u)  ? e4 : 0.f;
                const float p5 = (byte & 32u)  ? e5 : 0.f;
                const float p6 = (byte & 64u)  ? e6 : 0.f;
                const float p7 = (byte & 128u) ? e7 : 0.f;
                bf16x8 aP;
                aP[0] = (__bf16)p0; aP[1] = (__bf16)p1; aP[2] = (__bf16)p2; aP[3] = (__bf16)p3;
                aP[4] = (__bf16)p4; aP[5] = (__bf16)p5; aP[6] = (__bf16)p6; aP[7] = (__bf16)p7;
                accz[m] = __builtin_amdgcn_mfma_f32_16x16x32_bf16(aP, ones, accz[m], 0, 0, 0);
#pragma unroll
                for (int n = 0; n < 4; ++n)
                    acc[m][n] = __builtin_amdgcn_mfma_f32_16x16x32_bf16(aP, bX[n], acc[m][n], 0, 0, 0);
            }
        }
    }

    // ---- 2-phase x 3-round LDS tree reduce across 8 waves ----
#pragma unroll
    for (int m = 0; m < 2; ++m) {
        if (wv >= 4) {
#pragma unroll
            for (int n = 0; n < 4; ++n)
#pragma unroll
                for (int r = 0; r < 4; ++r)
                    rb[wv - 4][l][n * 4 + r] = acc[m][n][r];
#pragma unroll
            for (int r = 0; r < 4; ++r)
                rb[wv - 4][l][16 + r] = accz[m][r];
        }
        __syncthreads();
        if (wv < 4) {
#pragma unroll
            for (int n = 0; n < 4; ++n)
#pragma unroll
                for (int r = 0; r < 4; ++r)
                    acc[m][n][r] += rb[wv][l][n * 4 + r];
#pragma unroll
            for (int r = 0; r < 4; ++r)
                accz[m][r] += rb[wv][l][16 + r];
        }
        __syncthreads();
        if (wv >= 2 && wv < 4) {
#pragma unroll
            for (int n = 0; n < 4; ++n)
#pragma unroll
                for (int r = 0; r < 4; ++r)
                    rb[wv - 2][l][n * 4 + r] = acc[m][n][r];
#pragma unroll
            for (int r = 0; r < 4; ++r)
                rb[wv - 2][l][16 + r] = accz[m][r];
        }
        __syncthreads();
        if (wv < 2) {
#pragma unroll
            for (int n = 0; n < 4; ++n)
#pragma unroll
                for (int r = 0; r < 4; ++r)
                    acc[m][n][r] += rb[wv][l][n * 4 + r];
#pragma unroll
            for (int r = 0; r < 4; ++r)
                accz[m][r] += rb[wv][l][16 + r];
        }
        __syncthreads();
        if (wv == 1) {
#pragma unroll
            for (int n = 0; n < 4; ++n)
#pragma unroll
                for (int r = 0; r < 4; ++r)
                    rb[0][l][n * 4 + r] = acc[m][n][r];
#pragma unroll
            for (int r = 0; r < 4; ++r)
                rb[0][l][16 + r] = accz[m][r];
        }
        __syncthreads();
        if (wv == 0) {
#pragma unroll
            for (int r = 0; r < 4; ++r) {
                const float zf = accz[m][r] + rb[0][l][16 + r];
                const float zr = __builtin_amdgcn_rcpf(zf);
                const int row = i0 + m * 16 + hi * 4 + r;
#pragma unroll
                for (int n = 0; n < 4; ++n) {
                    const float o = (acc[m][n][r] + rb[0][l][n * 4 + r]) * zr;
                    out[row * HC + h * CC + n * 16 + lo] = o > 0.f ? o : 0.f;
                }
            }
        }
        if (m == 0) __syncthreads();   // protect buffer reuse for phase 1
    }
}

extern "C" void kernel_launch(void* const* d_in, const int* in_sizes, int n_in,
                              void* d_out, int out_size, void* d_ws, size_t ws_size,
                              hipStream_t stream)
{
    const float* x    = (const float*)d_in[0];
    const int*   adj  = (const int*)d_in[1];
    const float* W    = (const float*)d_in[2];
    const float* bias = (const float*)d_in[3];
    const float* attl = (const float*)d_in[4];
    const float* attr = (const float*)d_in[5];
    float* out = (float*)d_out;

    char* ws = (char*)d_ws;
    __bf16* xlT  = (__bf16*)(ws);                               // 4 MB
    float*  alT  = (float*)(ws + (4u << 20));                   // 128 KB
    float*  arT  = (float*)(ws + (4u << 20) + (128u << 10));    // 128 KB
    u64*    abit = (u64*)(ws + (4u << 20) + (256u << 10));      // 2 MB

    kA<<<dim3(GEMM_BLOCKS + PACK_BLOCKS), 256, 0, stream>>>(
        adj, abit, x, W, bias, attl, attr, xlT, alT, arT);
    k3_attn<<<dim3(NH, NN / 32), 512, 0, stream>>>(abit, xlT, alT, arT, out);
}

// Round 6
// 114.839 us; speedup vs baseline: 1.5392x; 1.0124x over previous
//
#include <hip/hip_runtime.h>
#include <hip/hip_bf16.h>

// GATConv on MI355X.
// Pipeline (2 kernels):
//   kA: blocks [0,512): x_l tile GEMM (bf16 MFMA) + fused transpose->xlT and
//       per-head alpha_l/alpha_r (alpha_l pre-scaled by log2e).
//       blocks [512,4608): pack adj (64MB int32) -> 2MB bitmask, TRANSPOSED
//       tile layout [i-tile 32][jword 64][row-in-tile 32] so k3's mask load is
//       a 2-line coalesced read instead of a 32-line gather.
//   k3: block = (head, i-tile 32), 8 waves = 8 j-eighths (512 j each).
//       All inner-loop global reads are NONTEMPORAL (L1 no-allocate: the
//       512KB/block working set thrashes 32KB L1; L2 per XCD holds it).
//       it-loop fully unrolled for cross-iteration load ILP.
//       P = bit ? exp2(al2*ar) : 0 in MFMA A-frag layout; acc += P @ x_l;
//       Z via MFMA ones-B. 2-phase x 3-round LDS tree reduce,
//       out = relu(acc*rcp(Z)).
//   grid.x = 8 heads = 8 XCDs -> round-robin dispatch gives per-head L2 locality.

#define NN    4096
#define NF    512
#define NH    8
#define CC    64
#define HC    512   // NH*CC
#define GEMM_BLOCKS 512
#define PACK_BLOCKS 4096

typedef __bf16 bf16x8 __attribute__((ext_vector_type(8)));
typedef __bf16 bf16x4 __attribute__((ext_vector_type(4)));
typedef float  f32x4  __attribute__((ext_vector_type(4)));
typedef unsigned long long u64;

#define NTL(p) __builtin_nontemporal_load(p)

__device__ __forceinline__ float exp2_raw(float x) {
    float r;
    asm("v_exp_f32 %0, %1" : "=v"(r) : "v"(x));
    return r;
}

// ---------------- kA: fused pack + projection GEMM + transpose/alpha ----------------
__global__ __launch_bounds__(256) void kA(
    const int* __restrict__ adj, u64* __restrict__ bits,
    const float* __restrict__ X, const float* __restrict__ W,
    const float* __restrict__ bias, const float* __restrict__ attl,
    const float* __restrict__ attr, __bf16* __restrict__ xlT,
    float* __restrict__ alT, float* __restrict__ arT)
{
    const int tid = threadIdx.x;

    if (blockIdx.x >= GEMM_BLOCKS) {
        // ---- pack path: pure streaming, overlaps with GEMM blocks ----
        // store layout: [i>>5][jw][i&31]  (tile-transposed for k3's coalesced read)
        const int bid = blockIdx.x - GEMM_BLOCKS;
        const int stride = PACK_BLOCKS * 256;
        for (int t = bid * 256 + tid; t < NN * NN; t += stride) {
            u64 m = __ballot(adj[t] != 0);
            if ((tid & 63) == 0) {
                const int i  = t >> 12;          // row
                const int jw = (t & 4095) >> 6;  // 64-col word
                bits[((i >> 5) * 64 + jw) * 32 + (i & 31)] = m;
            }
        }
        return;
    }

    // ---- GEMM path: one (64-row, 1-head) tile ----
    __shared__ __bf16 As[64][40];
    __shared__ __bf16 BsT[64][40];
    __shared__ __bf16 T[64][72];

    const int w  = tid >> 6;
    const int l  = tid & 63;
    const int lo = l & 15;
    const int hi = l >> 4;
    const int r0 = (blockIdx.x & 63) * 64;
    const int h  = blockIdx.x >> 6;
    const int c0 = h * CC;
    const int wm = (w >> 1) * 32;
    const int wn = (w & 1) * 32;

    f32x4 acc[2][2];
#pragma unroll
    for (int m = 0; m < 2; ++m)
#pragma unroll
        for (int n = 0; n < 2; ++n) acc[m][n] = (f32x4){0.f, 0.f, 0.f, 0.f};

    const int arow = tid >> 3;
    const int acol = (tid & 7) * 4;
    const int brow = tid >> 4;
    const int bcol = (tid & 15) * 4;

    for (int k0 = 0; k0 < NF; k0 += 32) {
        __syncthreads();
#pragma unroll
        for (int p = 0; p < 2; ++p) {
            int r = arow + p * 32;
            float4 v = *reinterpret_cast<const float4*>(&X[(r0 + r) * NF + k0 + acol]);
            bf16x4 av;
            av[0] = (__bf16)v.x; av[1] = (__bf16)v.y; av[2] = (__bf16)v.z; av[3] = (__bf16)v.w;
            *reinterpret_cast<bf16x4*>(&As[r][acol]) = av;
        }
#pragma unroll
        for (int p = 0; p < 2; ++p) {
            int kk = brow + p * 16;
            float4 v = *reinterpret_cast<const float4*>(&W[(k0 + kk) * HC + c0 + bcol]);
            BsT[bcol + 0][kk] = (__bf16)v.x;
            BsT[bcol + 1][kk] = (__bf16)v.y;
            BsT[bcol + 2][kk] = (__bf16)v.z;
            BsT[bcol + 3][kk] = (__bf16)v.w;
        }
        __syncthreads();

        bf16x8 a[2], b[2];
#pragma unroll
        for (int m = 0; m < 2; ++m)
            a[m] = *reinterpret_cast<const bf16x8*>(&As[wm + m * 16 + lo][hi * 8]);
#pragma unroll
        for (int n = 0; n < 2; ++n)
            b[n] = *reinterpret_cast<const bf16x8*>(&BsT[wn + n * 16 + lo][hi * 8]);
#pragma unroll
        for (int m = 0; m < 2; ++m)
#pragma unroll
            for (int n = 0; n < 2; ++n)
                acc[m][n] = __builtin_amdgcn_mfma_f32_16x16x32_bf16(a[m], b[n], acc[m][n], 0, 0, 0);
    }

    // epilogue: bias + bf16 round into LDS tile T (row-major)
    __syncthreads();
#pragma unroll
    for (int n = 0; n < 2; ++n) {
        const float bv = bias[c0 + wn + n * 16 + lo];
#pragma unroll
        for (int m = 0; m < 2; ++m)
#pragma unroll
            for (int r = 0; r < 4; ++r)
                T[wm + m * 16 + hi * 4 + r][wn + n * 16 + lo] = (__bf16)(acc[m][n][r] + bv);
    }
    __syncthreads();

    // transposed, coalesced store to xlT
    {
        const int cc_  = tid >> 3;
        const int row8 = (tid & 7) * 8;
#pragma unroll
        for (int p = 0; p < 2; ++p) {
            int cc = cc_ + p * 32;
            bf16x8 g;
#pragma unroll
            for (int j = 0; j < 8; ++j) g[j] = T[row8 + j][cc];
            *reinterpret_cast<bf16x8*>(&xlT[(c0 + cc) * NN + r0 + row8]) = g;
        }
    }
    // alpha_l (scaled by log2e) / alpha_r for these 64 rows
    {
        const int row = tid >> 2;
        const int q   = tid & 3;
        float pl = 0.f, pr = 0.f;
#pragma unroll
        for (int c = 0; c < 16; ++c) {
            const int cc = q * 16 + c;
            const float f = (float)T[row][cc];
            pl += f * attl[c0 + cc];
            pr += f * attr[c0 + cc];
        }
        pl += __shfl_xor(pl, 1); pl += __shfl_xor(pl, 2);
        pr += __shfl_xor(pr, 1); pr += __shfl_xor(pr, 2);
        if (q == 0) {
            alT[h * NN + r0 + row] = pl * 1.4426950408889634f;
            arT[h * NN + r0 + row] = pr;
        }
    }
}

// ---------------- k3: fused mask+exp+aggregate+Z+normalize+ReLU ----------------
__global__ __launch_bounds__(512) void k3_attn(
    const u64* __restrict__ bitsT, const __bf16* __restrict__ xlT,
    const float* __restrict__ alT, const float* __restrict__ arT,
    float* __restrict__ out)
{
    // 2 phases (m=0,1), 3-round tree over 8 waves; payload 20 floats
    __shared__ float rb[4][64][21];   // [slot][lane][payload+pad] = 21.5 KB

    const int tid = threadIdx.x;
    const int wv  = tid >> 6;        // 8 waves : j-eighths
    const int l   = tid & 63;
    const int lo  = l & 15;
    const int hi  = l >> 4;
    const int h   = blockIdx.x;      // head (== XCD via round-robin dispatch)
    const int i0  = blockIdx.y * 32;

    const float al20 = alT[h * NN + i0 + lo];
    const float al21 = alT[h * NN + i0 + 16 + lo];

    f32x4 acc[2][4];
    f32x4 accz[2];
#pragma unroll
    for (int m = 0; m < 2; ++m) {
        accz[m] = (f32x4){0.f, 0.f, 0.f, 0.f};
#pragma unroll
        for (int n = 0; n < 4; ++n) acc[m][n] = (f32x4){0.f, 0.f, 0.f, 0.f};
    }
    bf16x8 ones;
#pragma unroll
    for (int j = 0; j < 8; ++j) ones[j] = (__bf16)1.0f;

    // transposed-tile bitmask: [i-tile][jw][32 rows] -> 2-line coalesced loads
    const u64* bT = bitsT + (size_t)blockIdx.y * 64 * 32;
    const float* arp = &arT[h * NN];
    const __bf16* xp = &xlT[(size_t)(h * CC) * NN];
    const int w0 = wv * 8;           // 8 u64 words per eighth (512 j)

#pragma unroll
    for (int it = 0; it < 8; ++it) {
        const int jw = w0 + it;
        const u64 ab0 = NTL(&bT[jw * 32 + lo]);
        const u64 ab1 = NTL(&bT[jw * 32 + 16 + lo]);
        const int j0 = jw * 64;
#pragma unroll
        for (int s = 0; s < 2; ++s) {
            const int jj = j0 + s * 32 + hi * 8;
            const f32x4 rv0 = NTL(reinterpret_cast<const f32x4*>(arp + jj));
            const f32x4 rv1 = NTL(reinterpret_cast<const f32x4*>(arp + jj + 4));
            bf16x8 bX[4];
#pragma unroll
            for (int n = 0; n < 4; ++n)
                bX[n] = NTL(reinterpret_cast<const bf16x8*>(&xp[(n * 16 + lo) * NN + jj]));
            const int sh = s * 32 + hi * 8;
#pragma unroll
            for (int m = 0; m < 2; ++m) {
                const unsigned int byte = (unsigned int)(((m ? ab1 : ab0) >> sh) & 0xffULL);
                const float alm = m ? al21 : al20;
                // branchless: exp always computed, cndmask-selected
                const float e0 = exp2_raw(alm * rv0[0]);
                const float e1 = exp2_raw(alm * rv0[1]);
                const float e2 = exp2_raw(alm * rv0[2]);
                const float e3 = exp2_raw(alm * rv0[3]);
                const float e4 = exp2_raw(alm * rv1[0]);
                const float e5 = exp2_raw(alm * rv1[1]);
                const float e6 = exp2_raw(alm * rv1[2]);
                const float e7 = exp2_raw(alm * rv1[3]);
                const float p0 = (byte & 1u)   ? e0 : 0.f;
                const float p1 = (byte & 2u)   ? e1 : 0.f;
                const float p2 = (byte & 4u)   ? e2 : 0.f;
                const float p3 = (byte & 8u)   ? e3 : 0.f;
                const float p4 = (byte & 16u)  ? e4 : 0.f;
                const float p5 = (byte & 32u)  ? e5 : 0.f;
                const float p6 = (byte & 64u)  ? e6 : 0.f;
                const float p7 = (byte & 128u) ? e7 : 0.f;
                bf16x8 aP;
                aP[0] = (__bf16)p0; aP[1] = (__bf16)p1; aP[2] = (__bf16)p2; aP[3] = (__bf16)p3;
                aP[4] = (__bf16)p4; aP[5] = (__bf16)p5; aP[6] = (__bf16)p6; aP[7] = (__bf16)p7;
                accz[m] = __builtin_amdgcn_mfma_f32_16x16x32_bf16(aP, ones, accz[m], 0, 0, 0);
#pragma unroll
                for (int n = 0; n < 4; ++n)
                    acc[m][n] = __builtin_amdgcn_mfma_f32_16x16x32_bf16(aP, bX[n], acc[m][n], 0, 0, 0);
            }
        }
    }

    // ---- 2-phase x 3-round LDS tree reduce across 8 waves ----
#pragma unroll
    for (int m = 0; m < 2; ++m) {
        if (wv >= 4) {
#pragma unroll
            for (int n = 0; n < 4; ++n)
#pragma unroll
                for (int r = 0; r < 4; ++r)
                    rb[wv - 4][l][n * 4 + r] = acc[m][n][r];
#pragma unroll
            for (int r = 0; r < 4; ++r)
                rb[wv - 4][l][16 + r] = accz[m][r];
        }
        __syncthreads();
        if (wv < 4) {
#pragma unroll
            for (int n = 0; n < 4; ++n)
#pragma unroll
                for (int r = 0; r < 4; ++r)
                    acc[m][n][r] += rb[wv][l][n * 4 + r];
#pragma unroll
            for (int r = 0; r < 4; ++r)
                accz[m][r] += rb[wv][l][16 + r];
        }
        __syncthreads();
        if (wv >= 2 && wv < 4) {
#pragma unroll
            for (int n = 0; n < 4; ++n)
#pragma unroll
                for (int r = 0; r < 4; ++r)
                    rb[wv - 2][l][n * 4 + r] = acc[m][n][r];
#pragma unroll
            for (int r = 0; r < 4; ++r)
                rb[wv - 2][l][16 + r] = accz[m][r];
        }
        __syncthreads();
        if (wv < 2) {
#pragma unroll
            for (int n = 0; n < 4; ++n)
#pragma unroll
                for (int r = 0; r < 4; ++r)
                    acc[m][n][r] += rb[wv][l][n * 4 + r];
#pragma unroll
            for (int r = 0; r < 4; ++r)
                accz[m][r] += rb[wv][l][16 + r];
        }
        __syncthreads();
        if (wv == 1) {
#pragma unroll
            for (int n = 0; n < 4; ++n)
#pragma unroll
                for (int r = 0; r < 4; ++r)
                    rb[0][l][n * 4 + r] = acc[m][n][r];
#pragma unroll
            for (int r = 0; r < 4; ++r)
                rb[0][l][16 + r] = accz[m][r];
        }
        __syncthreads();
        if (wv == 0) {
#pragma unroll
            for (int r = 0; r < 4; ++r) {
                const float zf = accz[m][r] + rb[0][l][16 + r];
                const float zr = __builtin_amdgcn_rcpf(zf);
                const int row = i0 + m * 16 + hi * 4 + r;
#pragma unroll
                for (int n = 0; n < 4; ++n) {
                    const float o = (acc[m][n][r] + rb[0][l][n * 4 + r]) * zr;
                    out[row * HC + h * CC + n * 16 + lo] = o > 0.f ? o : 0.f;
                }
            }
        }
        if (m == 0) __syncthreads();   // protect buffer reuse for phase 1
    }
}

extern "C" void kernel_launch(void* const* d_in, const int* in_sizes, int n_in,
                              void* d_out, int out_size, void* d_ws, size_t ws_size,
                              hipStream_t stream)
{
    const float* x    = (const float*)d_in[0];
    const int*   adj  = (const int*)d_in[1];
    const float* W    = (const float*)d_in[2];
    const float* bias = (const float*)d_in[3];
    const float* attl = (const float*)d_in[4];
    const float* attr = (const float*)d_in[5];
    float* out = (float*)d_out;

    char* ws = (char*)d_ws;
    __bf16* xlT  = (__bf16*)(ws);                               // 4 MB
    float*  alT  = (float*)(ws + (4u << 20));                   // 128 KB
    float*  arT  = (float*)(ws + (4u << 20) + (128u << 10));    // 128 KB
    u64*    abit = (u64*)(ws + (4u << 20) + (256u << 10));      // 2 MB

    kA<<<dim3(GEMM_BLOCKS + PACK_BLOCKS), 256, 0, stream>>>(
        adj, abit, x, W, bias, attl, attr, xlT, alT, arT);
    k3_attn<<<dim3(NH, NN / 32), 512, 0, stream>>>(abit, xlT, alT, arT, out);
}

// Round 7
// 74.724 us; speedup vs baseline: 2.3655x; 1.5368x over previous
//
#include <hip/hip_runtime.h>
#include <hip/hip_bf16.h>

// GATConv on MI355X.
// Pipeline (2 kernels):
//   kA: blocks [0,512): x_l tile GEMM (bf16 MFMA); epilogue writes x_l DIRECTLY
//       in MFMA B-fragment order xlS[h][jw][s][n][lane][8] so k3's inner loads
//       are lane-contiguous 16B (perfectly coalesced 1KB/instr), plus per-head
//       alpha_l/alpha_r (alpha_l pre-scaled by log2e).
//       blocks [512,4608): pack adj (64MB int32) -> 2MB bitmask, tile-transposed
//       [i-tile 32][jword 64][row 32] for coalesced mask reads.
//   k3: block = (head, i-tile 32), 8 waves = 8 j-eighths (512 j each).
//       P = exp2(fma(al2, ar, bit ? 0 : -1000)) (exact 0 when masked, underflow)
//       in MFMA A-frag layout; acc += P @ x_l ; Z via MFMA ones-B.
//       2-phase x 3-round LDS tree reduce, out = relu(acc*rcp(Z)).
//   grid.x = 8 heads = 8 XCDs -> round-robin dispatch gives per-head L2 locality.

#define NN    4096
#define NF    512
#define NH    8
#define CC    64
#define HC    512   // NH*CC
#define GEMM_BLOCKS 512
#define PACK_BLOCKS 4096

typedef __bf16 bf16x8 __attribute__((ext_vector_type(8)));
typedef __bf16 bf16x4 __attribute__((ext_vector_type(4)));
typedef float  f32x4  __attribute__((ext_vector_type(4)));
typedef unsigned long long u64;

__device__ __forceinline__ float exp2_raw(float x) {
    float r;
    asm("v_exp_f32 %0, %1" : "=v"(r) : "v"(x));
    return r;
}

// ---------------- kA: fused pack + projection GEMM + frag-layout store ----------------
__global__ __launch_bounds__(256) void kA(
    const int* __restrict__ adj, u64* __restrict__ bits,
    const float* __restrict__ X, const float* __restrict__ W,
    const float* __restrict__ bias, const float* __restrict__ attl,
    const float* __restrict__ attr, __bf16* __restrict__ xlS,
    float* __restrict__ alT, float* __restrict__ arT)
{
    const int tid = threadIdx.x;

    if (blockIdx.x >= GEMM_BLOCKS) {
        // ---- pack path: pure streaming, overlaps with GEMM blocks ----
        // store layout: [i>>5][jw][i&31]  (tile-transposed for k3's coalesced read)
        const int bid = blockIdx.x - GEMM_BLOCKS;
        const int stride = PACK_BLOCKS * 256;
        for (int t = bid * 256 + tid; t < NN * NN; t += stride) {
            u64 m = __ballot(adj[t] != 0);
            if ((tid & 63) == 0) {
                const int i  = t >> 12;          // row
                const int jw = (t & 4095) >> 6;  // 64-col word
                bits[((i >> 5) * 64 + jw) * 32 + (i & 31)] = m;
            }
        }
        return;
    }

    // ---- GEMM path: one (64-node, 1-head) tile ----
    __shared__ __bf16 As[64][40];
    __shared__ __bf16 BsT[64][40];
    __shared__ __bf16 T[64][72];

    const int w  = tid >> 6;
    const int l  = tid & 63;
    const int lo = l & 15;
    const int hi = l >> 4;
    const int r0 = (blockIdx.x & 63) * 64;   // node base == jw*64
    const int h  = blockIdx.x >> 6;
    const int c0 = h * CC;
    const int wm = (w >> 1) * 32;
    const int wn = (w & 1) * 32;

    f32x4 acc[2][2];
#pragma unroll
    for (int m = 0; m < 2; ++m)
#pragma unroll
        for (int n = 0; n < 2; ++n) acc[m][n] = (f32x4){0.f, 0.f, 0.f, 0.f};

    const int arow = tid >> 3;
    const int acol = (tid & 7) * 4;
    const int brow = tid >> 4;
    const int bcol = (tid & 15) * 4;

    for (int k0 = 0; k0 < NF; k0 += 32) {
        __syncthreads();
#pragma unroll
        for (int p = 0; p < 2; ++p) {
            int r = arow + p * 32;
            float4 v = *reinterpret_cast<const float4*>(&X[(r0 + r) * NF + k0 + acol]);
            bf16x4 av;
            av[0] = (__bf16)v.x; av[1] = (__bf16)v.y; av[2] = (__bf16)v.z; av[3] = (__bf16)v.w;
            *reinterpret_cast<bf16x4*>(&As[r][acol]) = av;
        }
#pragma unroll
        for (int p = 0; p < 2; ++p) {
            int kk = brow + p * 16;
            float4 v = *reinterpret_cast<const float4*>(&W[(k0 + kk) * HC + c0 + bcol]);
            BsT[bcol + 0][kk] = (__bf16)v.x;
            BsT[bcol + 1][kk] = (__bf16)v.y;
            BsT[bcol + 2][kk] = (__bf16)v.z;
            BsT[bcol + 3][kk] = (__bf16)v.w;
        }
        __syncthreads();

        bf16x8 a[2], b[2];
#pragma unroll
        for (int m = 0; m < 2; ++m)
            a[m] = *reinterpret_cast<const bf16x8*>(&As[wm + m * 16 + lo][hi * 8]);
#pragma unroll
        for (int n = 0; n < 2; ++n)
            b[n] = *reinterpret_cast<const bf16x8*>(&BsT[wn + n * 16 + lo][hi * 8]);
#pragma unroll
        for (int m = 0; m < 2; ++m)
#pragma unroll
            for (int n = 0; n < 2; ++n)
                acc[m][n] = __builtin_amdgcn_mfma_f32_16x16x32_bf16(a[m], b[n], acc[m][n], 0, 0, 0);
    }

    // epilogue: bias + bf16 round into LDS tile T[node-in-tile][channel]
    __syncthreads();
#pragma unroll
    for (int n = 0; n < 2; ++n) {
        const float bv = bias[c0 + wn + n * 16 + lo];
#pragma unroll
        for (int m = 0; m < 2; ++m)
#pragma unroll
            for (int r = 0; r < 4; ++r)
                T[wm + m * 16 + hi * 4 + r][wn + n * 16 + lo] = (__bf16)(acc[m][n][r] + bv);
    }
    __syncthreads();

    // store in k3's B-fragment order: xlS[((h*64+jw)*2+s)*4+n][lane][8]
    // content: lane reads channel n*16+(lane&15) of nodes jw*64+s*32+(lane>>4)*8+e
    {
        const int jw = blockIdx.x & 63;
#pragma unroll
        for (int p = 0; p < 2; ++p) {
            const int z   = tid + p * 256;
            const int s   = z >> 8;
            const int n   = (z >> 6) & 3;
            const int ln  = z & 63;
            const int hi2 = ln >> 4;
            const int lo2 = ln & 15;
            bf16x8 g;
#pragma unroll
            for (int e = 0; e < 8; ++e)
                g[e] = T[s * 32 + hi2 * 8 + e][n * 16 + lo2];
            *reinterpret_cast<bf16x8*>(
                &xlS[(size_t)((((h * 64 + jw) * 2 + s) * 4 + n) * 64 + ln) * 8]) = g;
        }
    }
    // alpha_l (scaled by log2e) / alpha_r for these 64 nodes
    {
        const int row = tid >> 2;
        const int q   = tid & 3;
        float pl = 0.f, pr = 0.f;
#pragma unroll
        for (int c = 0; c < 16; ++c) {
            const int cc = q * 16 + c;
            const float f = (float)T[row][cc];
            pl += f * attl[c0 + cc];
            pr += f * attr[c0 + cc];
        }
        pl += __shfl_xor(pl, 1); pl += __shfl_xor(pl, 2);
        pr += __shfl_xor(pr, 1); pr += __shfl_xor(pr, 2);
        if (q == 0) {
            alT[h * NN + r0 + row] = pl * 1.4426950408889634f;
            arT[h * NN + r0 + row] = pr;
        }
    }
}

// ---------------- k3: fused mask+exp+aggregate+Z+normalize+ReLU ----------------
__global__ __launch_bounds__(512) void k3_attn(
    const u64* __restrict__ bitsT, const __bf16* __restrict__ xlS,
    const float* __restrict__ alT, const float* __restrict__ arT,
    float* __restrict__ out)
{
    // 2 phases (m=0,1), 3-round tree over 8 waves; payload 20 floats
    __shared__ float rb[4][64][21];   // [slot][lane][payload+pad] = 21.5 KB

    const int tid = threadIdx.x;
    const int wv  = tid >> 6;        // 8 waves : j-eighths
    const int l   = tid & 63;
    const int lo  = l & 15;
    const int hi  = l >> 4;
    const int h   = blockIdx.x;      // head (== XCD via round-robin dispatch)
    const int i0  = blockIdx.y * 32;

    const float al20 = alT[h * NN + i0 + lo];
    const float al21 = alT[h * NN + i0 + 16 + lo];

    f32x4 acc[2][4];
    f32x4 accz[2];
#pragma unroll
    for (int m = 0; m < 2; ++m) {
        accz[m] = (f32x4){0.f, 0.f, 0.f, 0.f};
#pragma unroll
        for (int n = 0; n < 4; ++n) acc[m][n] = (f32x4){0.f, 0.f, 0.f, 0.f};
    }
    bf16x8 ones;
#pragma unroll
    for (int j = 0; j < 8; ++j) ones[j] = (__bf16)1.0f;

    // tile-transposed bitmask: [i-tile][jw][32 rows] -> 2-line coalesced loads
    const u64* bT = bitsT + (size_t)blockIdx.y * 64 * 32;
    const float* arp = &arT[h * NN];
    const __bf16* xs = xlS + (size_t)h * 64 * 4096;  // per-jw chunk = 2*4*64*8 = 4096 elems
    const int w0 = wv * 8;           // 8 u64 words per eighth (512 j)

#pragma unroll
    for (int it = 0; it < 8; ++it) {
        const int jw = w0 + it;
        const u64 ab0 = bT[jw * 32 + lo];
        const u64 ab1 = bT[jw * 32 + 16 + lo];
#pragma unroll
        for (int s = 0; s < 2; ++s) {
            const int jj = jw * 64 + s * 32 + hi * 8;
            const f32x4 rv0 = *reinterpret_cast<const f32x4*>(arp + jj);
            const f32x4 rv1 = *reinterpret_cast<const f32x4*>(arp + jj + 4);
            bf16x8 bX[4];
#pragma unroll
            for (int n = 0; n < 4; ++n)
                bX[n] = *reinterpret_cast<const bf16x8*>(
                    &xs[(size_t)(((jw * 2 + s) * 4 + n) * 64 + l) * 8]);
            const int sh = s * 32 + hi * 8;
#pragma unroll
            for (int m = 0; m < 2; ++m) {
                const unsigned int byte = (unsigned int)(((m ? ab1 : ab0) >> sh) & 0xffULL);
                const float alm = m ? al21 : al20;
                // mask folded into exp input: exp2(-1000+x) underflows to exact 0
                const float b0 = (byte & 1u)   ? 0.f : -1000.f;
                const float b1 = (byte & 2u)   ? 0.f : -1000.f;
                const float b2 = (byte & 4u)   ? 0.f : -1000.f;
                const float b3 = (byte & 8u)   ? 0.f : -1000.f;
                const float b4 = (byte & 16u)  ? 0.f : -1000.f;
                const float b5 = (byte & 32u)  ? 0.f : -1000.f;
                const float b6 = (byte & 64u)  ? 0.f : -1000.f;
                const float b7 = (byte & 128u) ? 0.f : -1000.f;
                const float p0 = exp2_raw(__builtin_fmaf(alm, rv0[0], b0));
                const float p1 = exp2_raw(__builtin_fmaf(alm, rv0[1], b1));
                const float p2 = exp2_raw(__builtin_fmaf(alm, rv0[2], b2));
                const float p3 = exp2_raw(__builtin_fmaf(alm, rv0[3], b3));
                const float p4 = exp2_raw(__builtin_fmaf(alm, rv1[0], b4));
                const float p5 = exp2_raw(__builtin_fmaf(alm, rv1[1], b5));
                const float p6 = exp2_raw(__builtin_fmaf(alm, rv1[2], b6));
                const float p7 = exp2_raw(__builtin_fmaf(alm, rv1[3], b7));
                bf16x8 aP;
                aP[0] = (__bf16)p0; aP[1] = (__bf16)p1; aP[2] = (__bf16)p2; aP[3] = (__bf16)p3;
                aP[4] = (__bf16)p4; aP[5] = (__bf16)p5; aP[6] = (__bf16)p6; aP[7] = (__bf16)p7;
                accz[m] = __builtin_amdgcn_mfma_f32_16x16x32_bf16(aP, ones, accz[m], 0, 0, 0);
#pragma unroll
                for (int n = 0; n < 4; ++n)
                    acc[m][n] = __builtin_amdgcn_mfma_f32_16x16x32_bf16(aP, bX[n], acc[m][n], 0, 0, 0);
            }
        }
    }

    // ---- 2-phase x 3-round LDS tree reduce across 8 waves ----
#pragma unroll
    for (int m = 0; m < 2; ++m) {
        if (wv >= 4) {
#pragma unroll
            for (int n = 0; n < 4; ++n)
#pragma unroll
                for (int r = 0; r < 4; ++r)
                    rb[wv - 4][l][n * 4 + r] = acc[m][n][r];
#pragma unroll
            for (int r = 0; r < 4; ++r)
                rb[wv - 4][l][16 + r] = accz[m][r];
        }
        __syncthreads();
        if (wv < 4) {
#pragma unroll
            for (int n = 0; n < 4; ++n)
#pragma unroll
                for (int r = 0; r < 4; ++r)
                    acc[m][n][r] += rb[wv][l][n * 4 + r];
#pragma unroll
            for (int r = 0; r < 4; ++r)
                accz[m][r] += rb[wv][l][16 + r];
        }
        __syncthreads();
        if (wv >= 2 && wv < 4) {
#pragma unroll
            for (int n = 0; n < 4; ++n)
#pragma unroll
                for (int r = 0; r < 4; ++r)
                    rb[wv - 2][l][n * 4 + r] = acc[m][n][r];
#pragma unroll
            for (int r = 0; r < 4; ++r)
                rb[wv - 2][l][16 + r] = accz[m][r];
        }
        __syncthreads();
        if (wv < 2) {
#pragma unroll
            for (int n = 0; n < 4; ++n)
#pragma unroll
                for (int r = 0; r < 4; ++r)
                    acc[m][n][r] += rb[wv][l][n * 4 + r];
#pragma unroll
            for (int r = 0; r < 4; ++r)
                accz[m][r] += rb[wv][l][16 + r];
        }
        __syncthreads();
        if (wv == 1) {
#pragma unroll
            for (int n = 0; n < 4; ++n)
#pragma unroll
                for (int r = 0; r < 4; ++r)
                    rb[0][l][n * 4 + r] = acc[m][n][r];
#pragma unroll
            for (int r = 0; r < 4; ++r)
                rb[0][l][16 + r] = accz[m][r];
        }
        __syncthreads();
        if (wv == 0) {
#pragma unroll
            for (int r = 0; r < 4; ++r) {
                const float zf = accz[m][r] + rb[0][l][16 + r];
                const float zr = __builtin_amdgcn_rcpf(zf);
                const int row = i0 + m * 16 + hi * 4 + r;
#pragma unroll
                for (int n = 0; n < 4; ++n) {
                    const float o = (acc[m][n][r] + rb[0][l][n * 4 + r]) * zr;
                    out[row * HC + h * CC + n * 16 + lo] = o > 0.f ? o : 0.f;
                }
            }
        }
        if (m == 0) __syncthreads();   // protect buffer reuse for phase 1
    }
}

extern "C" void kernel_launch(void* const* d_in, const int* in_sizes, int n_in,
                              void* d_out, int out_size, void* d_ws, size_t ws_size,
                              hipStream_t stream)
{
    const float* x    = (const float*)d_in[0];
    const int*   adj  = (const int*)d_in[1];
    const float* W    = (const float*)d_in[2];
    const float* bias = (const float*)d_in[3];
    const float* attl = (const float*)d_in[4];
    const float* attr = (const float*)d_in[5];
    float* out = (float*)d_out;

    char* ws = (char*)d_ws;
    __bf16* xlS  = (__bf16*)(ws);                               // 4 MB (frag layout)
    float*  alT  = (float*)(ws + (4u << 20));                   // 128 KB
    float*  arT  = (float*)(ws + (4u << 20) + (128u << 10));    // 128 KB
    u64*    abit = (u64*)(ws + (4u << 20) + (256u << 10));      // 2 MB

    kA<<<dim3(GEMM_BLOCKS + PACK_BLOCKS), 256, 0, stream>>>(
        adj, abit, x, W, bias, attl, attr, xlS, alT, arT);
    k3_attn<<<dim3(NH, NN / 32), 512, 0, stream>>>(abit, xlS, alT, arT, out);
}

// Round 8
// 74.004 us; speedup vs baseline: 2.3885x; 1.0097x over previous
//
#include <hip/hip_runtime.h>
#include <hip/hip_bf16.h>

// GATConv on MI355X.
// Pipeline (2 kernels):
//   kA: blocks [0,512): x_l tile GEMM (bf16 MFMA); epilogue writes x_l DIRECTLY
//       in MFMA B-fragment order xlS[h][jw][s][n][lane][8] (lane-contiguous 16B
//       loads in k3), plus per-head alpha_l/alpha_r (alpha_l pre-scaled log2e).
//       blocks [512,4608): pack adj (64MB int32); EXPAND variant writes AND-able
//       halfword masks (0xFFFF/0) directly in A-frag layout
//       mask32[itile][jw][s][m][lane][4dw] (32MB); fallback writes 2MB u64
//       bitmask (tile-transposed) when workspace is too small.
//   k3: block = (head, i-tile 32), 8 waves = 8 j-eighths. Inner loop:
//       p = exp2(al2*ar) -> bf16 pack -> 4x v_and with mask32 (0.5 VALU/elem
//       masking, replaces ~3/elem cndmask chain). acc += P @ x_l (MFMA);
//       Z via MFMA ones-B. 2-phase x 3-round LDS tree reduce,
//       out = relu(acc*rcp(Z)).
//   grid.x = 8 heads = 8 XCDs -> per-head L2 locality.

#define NN    4096
#define NF    512
#define NH    8
#define CC    64
#define HC    512   // NH*CC
#define GEMM_BLOCKS 512
#define PACK_BLOCKS 4096

typedef __bf16 bf16x8 __attribute__((ext_vector_type(8)));
typedef __bf16 bf16x4 __attribute__((ext_vector_type(4)));
typedef float  f32x4  __attribute__((ext_vector_type(4)));
typedef int    i32x4  __attribute__((ext_vector_type(4)));
typedef unsigned int u32;
typedef unsigned long long u64;

__device__ __forceinline__ float exp2_raw(float x) {
    float r;
    asm("v_exp_f32 %0, %1" : "=v"(r) : "v"(x));
    return r;
}

// ---------------- kA: fused pack + projection GEMM + frag-layout store ----------------
template<bool EXPAND>
__global__ __launch_bounds__(256) void kA(
    const int* __restrict__ adj, void* __restrict__ maskout,
    const float* __restrict__ X, const float* __restrict__ W,
    const float* __restrict__ bias, const float* __restrict__ attl,
    const float* __restrict__ attr, __bf16* __restrict__ xlS,
    float* __restrict__ alT, float* __restrict__ arT)
{
    const int tid = threadIdx.x;

    if (blockIdx.x >= GEMM_BLOCKS) {
        const int bid  = blockIdx.x - GEMM_BLOCKS;
        const int lane = tid & 63;
        const int wid  = bid * 4 + (tid >> 6);      // 16384 waves

        if (EXPAND) {
            // 8 rows x 1 jword per wave-iter: 8 independent loads (MLP), 8 ballots,
            // in-register expansion to A-frag halfword masks, 1 coalesced-ish store.
            u32* mk = (u32*)maskout;
            for (int u = wid; u < 32768; u += 16384) {   // (4096/8) * 64 units
                const int i0 = (u >> 6) * 8;
                const int jw = u & 63;
                const int ja = jw * 64 + lane;
                const u64 b0 = __ballot(adj[(i0 + 0) * NN + ja] != 0);
                const u64 b1 = __ballot(adj[(i0 + 1) * NN + ja] != 0);
                const u64 b2 = __ballot(adj[(i0 + 2) * NN + ja] != 0);
                const u64 b3 = __ballot(adj[(i0 + 3) * NN + ja] != 0);
                const u64 b4 = __ballot(adj[(i0 + 4) * NN + ja] != 0);
                const u64 b5 = __ballot(adj[(i0 + 5) * NN + ja] != 0);
                const u64 b6 = __ballot(adj[(i0 + 6) * NN + ja] != 0);
                const u64 b7 = __ballot(adj[(i0 + 7) * NN + ja] != 0);
                // lane c: row r = c&7, (s,hi) = c>>3  (all 64 lanes -> 64 chunks)
                const int r   = lane & 7;
                const int shi = lane >> 3;
                const u64 wr = (r < 4) ? ((r < 2) ? (r < 1 ? b0 : b1) : (r < 3 ? b2 : b3))
                                       : ((r < 6) ? (r < 5 ? b4 : b5) : (r < 7 ? b6 : b7));
                const u32 by = (u32)(wr >> (shi * 8)) & 0xffu;
                const u32 d0 = ((by & 1u)   ? 0xFFFFu : 0u) | ((by & 2u)   ? 0xFFFF0000u : 0u);
                const u32 d1 = ((by & 4u)   ? 0xFFFFu : 0u) | ((by & 8u)   ? 0xFFFF0000u : 0u);
                const u32 d2 = ((by & 16u)  ? 0xFFFFu : 0u) | ((by & 32u)  ? 0xFFFF0000u : 0u);
                const u32 d3 = ((by & 64u)  ? 0xFFFFu : 0u) | ((by & 128u) ? 0xFFFF0000u : 0u);
                const int i     = i0 + r;
                const int itile = i >> 5;
                const int mr    = (i >> 4) & 1;
                const int lo2   = i & 15;
                const int s2    = shi >> 2;
                const int hi2   = shi & 3;
                const u32 offd = (u32)(itile * 64 + jw) * 1024u + (u32)s2 * 512u
                               + (u32)mr * 256u + (u32)(hi2 * 16 + lo2) * 4u;
                i32x4 dv = (i32x4){(int)d0, (int)d1, (int)d2, (int)d3};
                *reinterpret_cast<i32x4*>(mk + offd) = dv;
            }
        } else {
            // fallback: u64 bitmask, tile-transposed [i>>5][jw][i&31]
            u64* bits = (u64*)maskout;
            const int stride = PACK_BLOCKS * 256;
            for (int t = bid * 256 + tid; t < NN * NN; t += stride) {
                u64 m = __ballot(adj[t] != 0);
                if ((tid & 63) == 0) {
                    const int i  = t >> 12;
                    const int jw = (t & 4095) >> 6;
                    bits[((i >> 5) * 64 + jw) * 32 + (i & 31)] = m;
                }
            }
        }
        return;
    }

    // ---- GEMM path: one (64-node, 1-head) tile ----
    __shared__ __bf16 As[64][40];
    __shared__ __bf16 BsT[64][40];
    __shared__ __bf16 T[64][72];

    const int w  = tid >> 6;
    const int l  = tid & 63;
    const int lo = l & 15;
    const int hi = l >> 4;
    const int r0 = (blockIdx.x & 63) * 64;   // node base == jw*64
    const int h  = blockIdx.x >> 6;
    const int c0 = h * CC;
    const int wm = (w >> 1) * 32;
    const int wn = (w & 1) * 32;

    f32x4 acc[2][2];
#pragma unroll
    for (int m = 0; m < 2; ++m)
#pragma unroll
        for (int n = 0; n < 2; ++n) acc[m][n] = (f32x4){0.f, 0.f, 0.f, 0.f};

    const int arow = tid >> 3;
    const int acol = (tid & 7) * 4;
    const int brow = tid >> 4;
    const int bcol = (tid & 15) * 4;

    for (int k0 = 0; k0 < NF; k0 += 32) {
        __syncthreads();
#pragma unroll
        for (int p = 0; p < 2; ++p) {
            int r = arow + p * 32;
            float4 v = *reinterpret_cast<const float4*>(&X[(r0 + r) * NF + k0 + acol]);
            bf16x4 av;
            av[0] = (__bf16)v.x; av[1] = (__bf16)v.y; av[2] = (__bf16)v.z; av[3] = (__bf16)v.w;
            *reinterpret_cast<bf16x4*>(&As[r][acol]) = av;
        }
#pragma unroll
        for (int p = 0; p < 2; ++p) {
            int kk = brow + p * 16;
            float4 v = *reinterpret_cast<const float4*>(&W[(k0 + kk) * HC + c0 + bcol]);
            BsT[bcol + 0][kk] = (__bf16)v.x;
            BsT[bcol + 1][kk] = (__bf16)v.y;
            BsT[bcol + 2][kk] = (__bf16)v.z;
            BsT[bcol + 3][kk] = (__bf16)v.w;
        }
        __syncthreads();

        bf16x8 a[2], b[2];
#pragma unroll
        for (int m = 0; m < 2; ++m)
            a[m] = *reinterpret_cast<const bf16x8*>(&As[wm + m * 16 + lo][hi * 8]);
#pragma unroll
        for (int n = 0; n < 2; ++n)
            b[n] = *reinterpret_cast<const bf16x8*>(&BsT[wn + n * 16 + lo][hi * 8]);
#pragma unroll
        for (int m = 0; m < 2; ++m)
#pragma unroll
            for (int n = 0; n < 2; ++n)
                acc[m][n] = __builtin_amdgcn_mfma_f32_16x16x32_bf16(a[m], b[n], acc[m][n], 0, 0, 0);
    }

    // epilogue: bias + bf16 round into LDS tile T[node-in-tile][channel]
    __syncthreads();
#pragma unroll
    for (int n = 0; n < 2; ++n) {
        const float bv = bias[c0 + wn + n * 16 + lo];
#pragma unroll
        for (int m = 0; m < 2; ++m)
#pragma unroll
            for (int r = 0; r < 4; ++r)
                T[wm + m * 16 + hi * 4 + r][wn + n * 16 + lo] = (__bf16)(acc[m][n][r] + bv);
    }
    __syncthreads();

    // store in k3's B-fragment order: xlS[((h*64+jw)*2+s)*4+n][lane][8]
    {
        const int jw = blockIdx.x & 63;
#pragma unroll
        for (int p = 0; p < 2; ++p) {
            const int z   = tid + p * 256;
            const int s   = z >> 8;
            const int n   = (z >> 6) & 3;
            const int ln  = z & 63;
            const int hi2 = ln >> 4;
            const int lo2 = ln & 15;
            bf16x8 g;
#pragma unroll
            for (int e = 0; e < 8; ++e)
                g[e] = T[s * 32 + hi2 * 8 + e][n * 16 + lo2];
            *reinterpret_cast<bf16x8*>(
                &xlS[(size_t)((((h * 64 + jw) * 2 + s) * 4 + n) * 64 + ln) * 8]) = g;
        }
    }
    // alpha_l (scaled by log2e) / alpha_r for these 64 nodes
    {
        const int row = tid >> 2;
        const int q   = tid & 3;
        float pl = 0.f, pr = 0.f;
#pragma unroll
        for (int c = 0; c < 16; ++c) {
            const int cc = q * 16 + c;
            const float f = (float)T[row][cc];
            pl += f * attl[c0 + cc];
            pr += f * attr[c0 + cc];
        }
        pl += __shfl_xor(pl, 1); pl += __shfl_xor(pl, 2);
        pr += __shfl_xor(pr, 1); pr += __shfl_xor(pr, 2);
        if (q == 0) {
            alT[h * NN + r0 + row] = pl * 1.4426950408889634f;
            arT[h * NN + r0 + row] = pr;
        }
    }
}

// ---------------- k3: fused mask+exp+aggregate+Z+normalize+ReLU ----------------
template<bool EXPAND>
__global__ __launch_bounds__(512) void k3_attn(
    const void* __restrict__ maskin, const __bf16* __restrict__ xlS,
    const float* __restrict__ alT, const float* __restrict__ arT,
    float* __restrict__ out)
{
    __shared__ float rb[4][64][21];   // [slot][lane][payload+pad] = 21.5 KB

    const int tid = threadIdx.x;
    const int wv  = tid >> 6;        // 8 waves : j-eighths
    const int l   = tid & 63;
    const int lo  = l & 15;
    const int hi  = l >> 4;
    const int h   = blockIdx.x;      // head (== XCD via round-robin dispatch)
    const int i0  = blockIdx.y * 32;

    const float al20 = alT[h * NN + i0 + lo];
    const float al21 = alT[h * NN + i0 + 16 + lo];

    f32x4 acc[2][4];
    f32x4 accz[2];
#pragma unroll
    for (int m = 0; m < 2; ++m) {
        accz[m] = (f32x4){0.f, 0.f, 0.f, 0.f};
#pragma unroll
        for (int n = 0; n < 4; ++n) acc[m][n] = (f32x4){0.f, 0.f, 0.f, 0.f};
    }
    bf16x8 ones;
#pragma unroll
    for (int j = 0; j < 8; ++j) ones[j] = (__bf16)1.0f;

    const float* arp = &arT[h * NN];
    const __bf16* xs = xlS + (size_t)h * (64 * 4096);
    const int w0 = wv * 8;

    if (EXPAND) {
        const u32* mkb = (const u32*)maskin + (u32)blockIdx.y * 65536u;  // itile slice
#pragma unroll
        for (int it = 0; it < 8; ++it) {
            const int jw = w0 + it;
#pragma unroll
            for (int s = 0; s < 2; ++s) {
                const int jj = jw * 64 + s * 32 + hi * 8;
                const f32x4 rv0 = *reinterpret_cast<const f32x4*>(arp + jj);
                const f32x4 rv1 = *reinterpret_cast<const f32x4*>(arp + jj + 4);
                bf16x8 bX[4];
#pragma unroll
                for (int n = 0; n < 4; ++n)
                    bX[n] = *reinterpret_cast<const bf16x8*>(
                        &xs[(jw * 2 + s) * 2048 + n * 512 + l * 8]);
                const u32* mp = mkb + jw * 1024 + s * 512 + l * 4;
                const i32x4 mk0 = *reinterpret_cast<const i32x4*>(mp);
                const i32x4 mk1 = *reinterpret_cast<const i32x4*>(mp + 256);
#pragma unroll
                for (int m = 0; m < 2; ++m) {
                    const float alm = m ? al21 : al20;
                    const float p0 = exp2_raw(alm * rv0[0]);
                    const float p1 = exp2_raw(alm * rv0[1]);
                    const float p2 = exp2_raw(alm * rv0[2]);
                    const float p3 = exp2_raw(alm * rv0[3]);
                    const float p4 = exp2_raw(alm * rv1[0]);
                    const float p5 = exp2_raw(alm * rv1[1]);
                    const float p6 = exp2_raw(alm * rv1[2]);
                    const float p7 = exp2_raw(alm * rv1[3]);
                    bf16x8 aP;
                    aP[0] = (__bf16)p0; aP[1] = (__bf16)p1; aP[2] = (__bf16)p2; aP[3] = (__bf16)p3;
                    aP[4] = (__bf16)p4; aP[5] = (__bf16)p5; aP[6] = (__bf16)p6; aP[7] = (__bf16)p7;
                    // bitwise AND mask: exact 0 on masked elements (handles inf too)
                    i32x4 ai = *reinterpret_cast<i32x4*>(&aP);
                    ai &= (m ? mk1 : mk0);
                    const bf16x8 aM = *reinterpret_cast<bf16x8*>(&ai);
                    accz[m] = __builtin_amdgcn_mfma_f32_16x16x32_bf16(aM, ones, accz[m], 0, 0, 0);
#pragma unroll
                    for (int n = 0; n < 4; ++n)
                        acc[m][n] = __builtin_amdgcn_mfma_f32_16x16x32_bf16(aM, bX[n], acc[m][n], 0, 0, 0);
                }
            }
        }
    } else {
        const u64* bT = (const u64*)maskin + (size_t)blockIdx.y * 64 * 32;
#pragma unroll
        for (int it = 0; it < 8; ++it) {
            const int jw = w0 + it;
            const u64 ab0 = bT[jw * 32 + lo];
            const u64 ab1 = bT[jw * 32 + 16 + lo];
#pragma unroll
            for (int s = 0; s < 2; ++s) {
                const int jj = jw * 64 + s * 32 + hi * 8;
                const f32x4 rv0 = *reinterpret_cast<const f32x4*>(arp + jj);
                const f32x4 rv1 = *reinterpret_cast<const f32x4*>(arp + jj + 4);
                bf16x8 bX[4];
#pragma unroll
                for (int n = 0; n < 4; ++n)
                    bX[n] = *reinterpret_cast<const bf16x8*>(
                        &xs[(jw * 2 + s) * 2048 + n * 512 + l * 8]);
                const int sh = s * 32 + hi * 8;
#pragma unroll
                for (int m = 0; m < 2; ++m) {
                    const u32 byte_ = (u32)(((m ? ab1 : ab0) >> sh) & 0xffULL);
                    const float alm = m ? al21 : al20;
                    const float b0 = (byte_ & 1u)   ? 0.f : -1000.f;
                    const float b1 = (byte_ & 2u)   ? 0.f : -1000.f;
                    const float b2 = (byte_ & 4u)   ? 0.f : -1000.f;
                    const float b3 = (byte_ & 8u)   ? 0.f : -1000.f;
                    const float b4 = (byte_ & 16u)  ? 0.f : -1000.f;
                    const float b5 = (byte_ & 32u)  ? 0.f : -1000.f;
                    const float b6 = (byte_ & 64u)  ? 0.f : -1000.f;
                    const float b7 = (byte_ & 128u) ? 0.f : -1000.f;
                    const float p0 = exp2_raw(__builtin_fmaf(alm, rv0[0], b0));
                    const float p1 = exp2_raw(__builtin_fmaf(alm, rv0[1], b1));
                    const float p2 = exp2_raw(__builtin_fmaf(alm, rv0[2], b2));
                    const float p3 = exp2_raw(__builtin_fmaf(alm, rv0[3], b3));
                    const float p4 = exp2_raw(__builtin_fmaf(alm, rv1[0], b4));
                    const float p5 = exp2_raw(__builtin_fmaf(alm, rv1[1], b5));
                    const float p6 = exp2_raw(__builtin_fmaf(alm, rv1[2], b6));
                    const float p7 = exp2_raw(__builtin_fmaf(alm, rv1[3], b7));
                    bf16x8 aP;
                    aP[0] = (__bf16)p0; aP[1] = (__bf16)p1; aP[2] = (__bf16)p2; aP[3] = (__bf16)p3;
                    aP[4] = (__bf16)p4; aP[5] = (__bf16)p5; aP[6] = (__bf16)p6; aP[7] = (__bf16)p7;
                    accz[m] = __builtin_amdgcn_mfma_f32_16x16x32_bf16(aP, ones, accz[m], 0, 0, 0);
#pragma unroll
                    for (int n = 0; n < 4; ++n)
                        acc[m][n] = __builtin_amdgcn_mfma_f32_16x16x32_bf16(aP, bX[n], acc[m][n], 0, 0, 0);
                }
            }
        }
    }

    // ---- 2-phase x 3-round LDS tree reduce across 8 waves ----
#pragma unroll
    for (int m = 0; m < 2; ++m) {
        if (wv >= 4) {
#pragma unroll
            for (int n = 0; n < 4; ++n)
#pragma unroll
                for (int r = 0; r < 4; ++r)
                    rb[wv - 4][l][n * 4 + r] = acc[m][n][r];
#pragma unroll
            for (int r = 0; r < 4; ++r)
                rb[wv - 4][l][16 + r] = accz[m][r];
        }
        __syncthreads();
        if (wv < 4) {
#pragma unroll
            for (int n = 0; n < 4; ++n)
#pragma unroll
                for (int r = 0; r < 4; ++r)
                    acc[m][n][r] += rb[wv][l][n * 4 + r];
#pragma unroll
            for (int r = 0; r < 4; ++r)
                accz[m][r] += rb[wv][l][16 + r];
        }
        __syncthreads();
        if (wv >= 2 && wv < 4) {
#pragma unroll
            for (int n = 0; n < 4; ++n)
#pragma unroll
                for (int r = 0; r < 4; ++r)
                    rb[wv - 2][l][n * 4 + r] = acc[m][n][r];
#pragma unroll
            for (int r = 0; r < 4; ++r)
                rb[wv - 2][l][16 + r] = accz[m][r];
        }
        __syncthreads();
        if (wv < 2) {
#pragma unroll
            for (int n = 0; n < 4; ++n)
#pragma unroll
                for (int r = 0; r < 4; ++r)
                    acc[m][n][r] += rb[wv][l][n * 4 + r];
#pragma unroll
            for (int r = 0; r < 4; ++r)
                accz[m][r] += rb[wv][l][16 + r];
        }
        __syncthreads();
        if (wv == 1) {
#pragma unroll
            for (int n = 0; n < 4; ++n)
#pragma unroll
                for (int r = 0; r < 4; ++r)
                    rb[0][l][n * 4 + r] = acc[m][n][r];
#pragma unroll
            for (int r = 0; r < 4; ++r)
                rb[0][l][16 + r] = accz[m][r];
        }
        __syncthreads();
        if (wv == 0) {
#pragma unroll
            for (int r = 0; r < 4; ++r) {
                const float zf = accz[m][r] + rb[0][l][16 + r];
                const float zr = __builtin_amdgcn_rcpf(zf);
                const int row = i0 + m * 16 + hi * 4 + r;
#pragma unroll
                for (int n = 0; n < 4; ++n) {
                    const float o = (acc[m][n][r] + rb[0][l][n * 4 + r]) * zr;
                    out[row * HC + h * CC + n * 16 + lo] = o > 0.f ? o : 0.f;
                }
            }
        }
        if (m == 0) __syncthreads();   // protect buffer reuse for phase 1
    }
}

extern "C" void kernel_launch(void* const* d_in, const int* in_sizes, int n_in,
                              void* d_out, int out_size, void* d_ws, size_t ws_size,
                              hipStream_t stream)
{
    const float* x    = (const float*)d_in[0];
    const int*   adj  = (const int*)d_in[1];
    const float* W    = (const float*)d_in[2];
    const float* bias = (const float*)d_in[3];
    const float* attl = (const float*)d_in[4];
    const float* attr = (const float*)d_in[5];
    float* out = (float*)d_out;

    char* ws = (char*)d_ws;
    __bf16* xlS = (__bf16*)(ws);                             // 4 MB (frag layout)
    float*  alT = (float*)(ws + (4u << 20));                 // 128 KB
    float*  arT = (float*)(ws + (4u << 20) + (128u << 10));  // 128 KB
    void*   msk = (void*)(ws + (4u << 20) + (256u << 10));   // 32 MB or 2 MB

    const size_t need_big = (4ull << 20) + (256ull << 10) + (32ull << 20);  // 36.25 MB

    if (ws_size >= need_big) {
        kA<true><<<dim3(GEMM_BLOCKS + PACK_BLOCKS), 256, 0, stream>>>(
            adj, msk, x, W, bias, attl, attr, xlS, alT, arT);
        k3_attn<true><<<dim3(NH, NN / 32), 512, 0, stream>>>(msk, xlS, alT, arT, out);
    } else {
        kA<false><<<dim3(GEMM_BLOCKS + PACK_BLOCKS), 256, 0, stream>>>(
            adj, msk, x, W, bias, attl, attr, xlS, alT, arT);
        k3_attn<false><<<dim3(NH, NN / 32), 512, 0, stream>>>(msk, xlS, alT, arT, out);
    }
}

// Round 9
// 70.611 us; speedup vs baseline: 2.5033x; 1.0481x over previous
//
#include <hip/hip_runtime.h>
#include <hip/hip_bf16.h>

// GATConv on MI355X.
// Pipeline (2 kernels):
//   kA: blocks [0,512): x_l tile GEMM (bf16 MFMA); epilogue writes x_l DIRECTLY
//       in MFMA B-fragment order xlS[h][jw][s][n][lane][8] (lane-contiguous 16B
//       loads in k3), plus per-head alpha_l/alpha_r (alpha_l pre-scaled log2e).
//       blocks [512,4608): pack adj (64MB int32) -> 2MB bitmask, tile-transposed
//       [i>>5][jw][i&31]; 8 rows/wave-iter for memory-level parallelism.
//   k3: block = (head, i-tile 64), 8 waves = 8 j-eighths. 4 m-groups of 16 rows
//       per block (TI=64 halves total xlS line traffic vs TI=32 -> the measured
//       limiter is per-CU cache-line service, not VALU/occupancy/HBM).
//       P = exp2(fma(al2, ar, bit ? 0 : -1000)) in MFMA A-frag layout;
//       acc += P @ x_l ; Z via MFMA ones-B. 4-phase x 3-round LDS tree reduce,
//       out = relu(acc*rcp(Z)).
//   grid.x = 8 heads = 8 XCDs -> per-head xlS L2 locality (bitmask is tiny).

#define NN    4096
#define NF    512
#define NH    8
#define CC    64
#define HC    512   // NH*CC
#define GEMM_BLOCKS 512
#define PACK_BLOCKS 4096

typedef __bf16 bf16x8 __attribute__((ext_vector_type(8)));
typedef __bf16 bf16x4 __attribute__((ext_vector_type(4)));
typedef float  f32x4  __attribute__((ext_vector_type(4)));
typedef unsigned int u32;
typedef unsigned long long u64;

__device__ __forceinline__ float exp2_raw(float x) {
    float r;
    asm("v_exp_f32 %0, %1" : "=v"(r) : "v"(x));
    return r;
}

// ---------------- kA: fused pack + projection GEMM + frag-layout store ----------------
__global__ __launch_bounds__(256) void kA(
    const int* __restrict__ adj, u64* __restrict__ bits,
    const float* __restrict__ X, const float* __restrict__ W,
    const float* __restrict__ bias, const float* __restrict__ attl,
    const float* __restrict__ attr, __bf16* __restrict__ xlS,
    float* __restrict__ alT, float* __restrict__ arT)
{
    const int tid = threadIdx.x;

    if (blockIdx.x >= GEMM_BLOCKS) {
        // ---- pack path: 8 rows per wave-iter (8 loads in flight), bitmask out ----
        const int bid  = blockIdx.x - GEMM_BLOCKS;
        const int lane = tid & 63;
        const int wid  = bid * 4 + (tid >> 6);      // 16384 waves
        for (int u = wid; u < 32768; u += 16384) {  // (4096/8 rowgroups) * 64 jw
            const int i0 = (u >> 6) * 8;
            const int jw = u & 63;
            const int ja = jw * 64 + lane;
            const u64 b0 = __ballot(adj[(i0 + 0) * NN + ja] != 0);
            const u64 b1 = __ballot(adj[(i0 + 1) * NN + ja] != 0);
            const u64 b2 = __ballot(adj[(i0 + 2) * NN + ja] != 0);
            const u64 b3 = __ballot(adj[(i0 + 3) * NN + ja] != 0);
            const u64 b4 = __ballot(adj[(i0 + 4) * NN + ja] != 0);
            const u64 b5 = __ballot(adj[(i0 + 5) * NN + ja] != 0);
            const u64 b6 = __ballot(adj[(i0 + 6) * NN + ja] != 0);
            const u64 b7 = __ballot(adj[(i0 + 7) * NN + ja] != 0);
            if (lane < 8) {
                const int r = lane;
                const u64 wr = (r < 4) ? ((r < 2) ? (r < 1 ? b0 : b1) : (r < 3 ? b2 : b3))
                                       : ((r < 6) ? (r < 5 ? b4 : b5) : (r < 7 ? b6 : b7));
                const int i = i0 + r;
                // rows i0..i0+7 share the same 32-tile -> 64B-contiguous stores
                bits[((i >> 5) * 64 + jw) * 32 + (i & 31)] = wr;
            }
        }
        return;
    }

    // ---- GEMM path: one (64-node, 1-head) tile ----
    __shared__ __bf16 As[64][40];
    __shared__ __bf16 BsT[64][40];
    __shared__ __bf16 T[64][72];

    const int w  = tid >> 6;
    const int l  = tid & 63;
    const int lo = l & 15;
    const int hi = l >> 4;
    const int r0 = (blockIdx.x & 63) * 64;   // node base == jw*64
    const int h  = blockIdx.x >> 6;
    const int c0 = h * CC;
    const int wm = (w >> 1) * 32;
    const int wn = (w & 1) * 32;

    f32x4 acc[2][2];
#pragma unroll
    for (int m = 0; m < 2; ++m)
#pragma unroll
        for (int n = 0; n < 2; ++n) acc[m][n] = (f32x4){0.f, 0.f, 0.f, 0.f};

    const int arow = tid >> 3;
    const int acol = (tid & 7) * 4;
    const int brow = tid >> 4;
    const int bcol = (tid & 15) * 4;

    for (int k0 = 0; k0 < NF; k0 += 32) {
        __syncthreads();
#pragma unroll
        for (int p = 0; p < 2; ++p) {
            int r = arow + p * 32;
            float4 v = *reinterpret_cast<const float4*>(&X[(r0 + r) * NF + k0 + acol]);
            bf16x4 av;
            av[0] = (__bf16)v.x; av[1] = (__bf16)v.y; av[2] = (__bf16)v.z; av[3] = (__bf16)v.w;
            *reinterpret_cast<bf16x4*>(&As[r][acol]) = av;
        }
#pragma unroll
        for (int p = 0; p < 2; ++p) {
            int kk = brow + p * 16;
            float4 v = *reinterpret_cast<const float4*>(&W[(k0 + kk) * HC + c0 + bcol]);
            BsT[bcol + 0][kk] = (__bf16)v.x;
            BsT[bcol + 1][kk] = (__bf16)v.y;
            BsT[bcol + 2][kk] = (__bf16)v.z;
            BsT[bcol + 3][kk] = (__bf16)v.w;
        }
        __syncthreads();

        bf16x8 a[2], b[2];
#pragma unroll
        for (int m = 0; m < 2; ++m)
            a[m] = *reinterpret_cast<const bf16x8*>(&As[wm + m * 16 + lo][hi * 8]);
#pragma unroll
        for (int n = 0; n < 2; ++n)
            b[n] = *reinterpret_cast<const bf16x8*>(&BsT[wn + n * 16 + lo][hi * 8]);
#pragma unroll
        for (int m = 0; m < 2; ++m)
#pragma unroll
            for (int n = 0; n < 2; ++n)
                acc[m][n] = __builtin_amdgcn_mfma_f32_16x16x32_bf16(a[m], b[n], acc[m][n], 0, 0, 0);
    }

    // epilogue: bias + bf16 round into LDS tile T[node-in-tile][channel]
    __syncthreads();
#pragma unroll
    for (int n = 0; n < 2; ++n) {
        const float bv = bias[c0 + wn + n * 16 + lo];
#pragma unroll
        for (int m = 0; m < 2; ++m)
#pragma unroll
            for (int r = 0; r < 4; ++r)
                T[wm + m * 16 + hi * 4 + r][wn + n * 16 + lo] = (__bf16)(acc[m][n][r] + bv);
    }
    __syncthreads();

    // store in k3's B-fragment order: xlS[((h*64+jw)*2+s)*4+n][lane][8]
    {
        const int jw = blockIdx.x & 63;
#pragma unroll
        for (int p = 0; p < 2; ++p) {
            const int z   = tid + p * 256;
            const int s   = z >> 8;
            const int n   = (z >> 6) & 3;
            const int ln  = z & 63;
            const int hi2 = ln >> 4;
            const int lo2 = ln & 15;
            bf16x8 g;
#pragma unroll
            for (int e = 0; e < 8; ++e)
                g[e] = T[s * 32 + hi2 * 8 + e][n * 16 + lo2];
            *reinterpret_cast<bf16x8*>(
                &xlS[(size_t)((((h * 64 + jw) * 2 + s) * 4 + n) * 64 + ln) * 8]) = g;
        }
    }
    // alpha_l (scaled by log2e) / alpha_r for these 64 nodes
    {
        const int row = tid >> 2;
        const int q   = tid & 3;
        float pl = 0.f, pr = 0.f;
#pragma unroll
        for (int c = 0; c < 16; ++c) {
            const int cc = q * 16 + c;
            const float f = (float)T[row][cc];
            pl += f * attl[c0 + cc];
            pr += f * attr[c0 + cc];
        }
        pl += __shfl_xor(pl, 1); pl += __shfl_xor(pl, 2);
        pr += __shfl_xor(pr, 1); pr += __shfl_xor(pr, 2);
        if (q == 0) {
            alT[h * NN + r0 + row] = pl * 1.4426950408889634f;
            arT[h * NN + r0 + row] = pr;
        }
    }
}

// ---------------- k3: fused mask+exp+aggregate+Z+normalize+ReLU ----------------
__global__ __launch_bounds__(512) void k3_attn(
    const u64* __restrict__ bits, const __bf16* __restrict__ xlS,
    const float* __restrict__ alT, const float* __restrict__ arT,
    float* __restrict__ out)
{
    __shared__ float rb[4][64][21];   // [slot][lane][payload+pad] = 21.5 KB

    const int tid = threadIdx.x;
    const int wv  = tid >> 6;        // 8 waves : j-eighths
    const int l   = tid & 63;
    const int lo  = l & 15;
    const int hi  = l >> 4;
    const int h   = blockIdx.x;      // head (== XCD via round-robin dispatch)
    const int by  = blockIdx.y;      // i-tile of 64 rows
    const int i0  = by * 64;

    float al2[4];
#pragma unroll
    for (int g = 0; g < 4; ++g) al2[g] = alT[h * NN + i0 + g * 16 + lo];

    f32x4 acc[4][4];
    f32x4 accz[4];
#pragma unroll
    for (int g = 0; g < 4; ++g) {
        accz[g] = (f32x4){0.f, 0.f, 0.f, 0.f};
#pragma unroll
        for (int n = 0; n < 4; ++n) acc[g][n] = (f32x4){0.f, 0.f, 0.f, 0.f};
    }
    bf16x8 ones;
#pragma unroll
    for (int j = 0; j < 8; ++j) ones[j] = (__bf16)1.0f;

    const float* arp = &arT[h * NN];
    const __bf16* xs = xlS + (size_t)h * (64 * 4096);
    const u64* bbase = bits + (size_t)(by * 2) * 64 * 32;  // two 32-row tiles
    const int w0 = wv * 8;

#pragma unroll
    for (int it = 0; it < 8; ++it) {
        const int jw = w0 + it;
        u64 ab[4];
#pragma unroll
        for (int g = 0; g < 4; ++g)
            ab[g] = bbase[((g >> 1) * 64 + jw) * 32 + (g & 1) * 16 + lo];
#pragma unroll
        for (int s = 0; s < 2; ++s) {
            const int jj = jw * 64 + s * 32 + hi * 8;
            const f32x4 rv0 = *reinterpret_cast<const f32x4*>(arp + jj);
            const f32x4 rv1 = *reinterpret_cast<const f32x4*>(arp + jj + 4);
            bf16x8 bX[4];
#pragma unroll
            for (int n = 0; n < 4; ++n)
                bX[n] = *reinterpret_cast<const bf16x8*>(
                    &xs[(jw * 2 + s) * 2048 + n * 512 + l * 8]);
            const int sh = s * 32 + hi * 8;
#pragma unroll
            for (int g = 0; g < 4; ++g) {
                const u32 byte_ = (u32)((ab[g] >> sh) & 0xffULL);
                const float alm = al2[g];
                const float b0 = (byte_ & 1u)   ? 0.f : -1000.f;
                const float b1 = (byte_ & 2u)   ? 0.f : -1000.f;
                const float b2 = (byte_ & 4u)   ? 0.f : -1000.f;
                const float b3 = (byte_ & 8u)   ? 0.f : -1000.f;
                const float b4 = (byte_ & 16u)  ? 0.f : -1000.f;
                const float b5 = (byte_ & 32u)  ? 0.f : -1000.f;
                const float b6 = (byte_ & 64u)  ? 0.f : -1000.f;
                const float b7 = (byte_ & 128u) ? 0.f : -1000.f;
                const float p0 = exp2_raw(__builtin_fmaf(alm, rv0[0], b0));
                const float p1 = exp2_raw(__builtin_fmaf(alm, rv0[1], b1));
                const float p2 = exp2_raw(__builtin_fmaf(alm, rv0[2], b2));
                const float p3 = exp2_raw(__builtin_fmaf(alm, rv0[3], b3));
                const float p4 = exp2_raw(__builtin_fmaf(alm, rv1[0], b4));
                const float p5 = exp2_raw(__builtin_fmaf(alm, rv1[1], b5));
                const float p6 = exp2_raw(__builtin_fmaf(alm, rv1[2], b6));
                const float p7 = exp2_raw(__builtin_fmaf(alm, rv1[3], b7));
                bf16x8 aP;
                aP[0] = (__bf16)p0; aP[1] = (__bf16)p1; aP[2] = (__bf16)p2; aP[3] = (__bf16)p3;
                aP[4] = (__bf16)p4; aP[5] = (__bf16)p5; aP[6] = (__bf16)p6; aP[7] = (__bf16)p7;
                accz[g] = __builtin_amdgcn_mfma_f32_16x16x32_bf16(aP, ones, accz[g], 0, 0, 0);
#pragma unroll
                for (int n = 0; n < 4; ++n)
                    acc[g][n] = __builtin_amdgcn_mfma_f32_16x16x32_bf16(aP, bX[n], acc[g][n], 0, 0, 0);
            }
        }
    }

    // ---- 4-phase (g) x 3-round LDS tree reduce across 8 waves ----
#pragma unroll
    for (int g = 0; g < 4; ++g) {
        if (wv >= 4) {
#pragma unroll
            for (int n = 0; n < 4; ++n)
#pragma unroll
                for (int r = 0; r < 4; ++r)
                    rb[wv - 4][l][n * 4 + r] = acc[g][n][r];
#pragma unroll
            for (int r = 0; r < 4; ++r)
                rb[wv - 4][l][16 + r] = accz[g][r];
        }
        __syncthreads();
        if (wv < 4) {
#pragma unroll
            for (int n = 0; n < 4; ++n)
#pragma unroll
                for (int r = 0; r < 4; ++r)
                    acc[g][n][r] += rb[wv][l][n * 4 + r];
#pragma unroll
            for (int r = 0; r < 4; ++r)
                accz[g][r] += rb[wv][l][16 + r];
        }
        __syncthreads();
        if (wv >= 2 && wv < 4) {
#pragma unroll
            for (int n = 0; n < 4; ++n)
#pragma unroll
                for (int r = 0; r < 4; ++r)
                    rb[wv - 2][l][n * 4 + r] = acc[g][n][r];
#pragma unroll
            for (int r = 0; r < 4; ++r)
                rb[wv - 2][l][16 + r] = accz[g][r];
        }
        __syncthreads();
        if (wv < 2) {
#pragma unroll
            for (int n = 0; n < 4; ++n)
#pragma unroll
                for (int r = 0; r < 4; ++r)
                    acc[g][n][r] += rb[wv][l][n * 4 + r];
#pragma unroll
            for (int r = 0; r < 4; ++r)
                accz[g][r] += rb[wv][l][16 + r];
        }
        __syncthreads();
        if (wv == 1) {
#pragma unroll
            for (int n = 0; n < 4; ++n)
#pragma unroll
                for (int r = 0; r < 4; ++r)
                    rb[0][l][n * 4 + r] = acc[g][n][r];
#pragma unroll
            for (int r = 0; r < 4; ++r)
                rb[0][l][16 + r] = accz[g][r];
        }
        __syncthreads();
        if (wv == 0) {
#pragma unroll
            for (int r = 0; r < 4; ++r) {
                const float zf = accz[g][r] + rb[0][l][16 + r];
                const float zr = __builtin_amdgcn_rcpf(zf);
                const int row = i0 + g * 16 + hi * 4 + r;
#pragma unroll
                for (int n = 0; n < 4; ++n) {
                    const float o = (acc[g][n][r] + rb[0][l][n * 4 + r]) * zr;
                    out[row * HC + h * CC + n * 16 + lo] = o > 0.f ? o : 0.f;
                }
            }
        }
        if (g < 3) __syncthreads();   // protect buffer reuse for next phase
    }
}

extern "C" void kernel_launch(void* const* d_in, const int* in_sizes, int n_in,
                              void* d_out, int out_size, void* d_ws, size_t ws_size,
                              hipStream_t stream)
{
    const float* x    = (const float*)d_in[0];
    const int*   adj  = (const int*)d_in[1];
    const float* W    = (const float*)d_in[2];
    const float* bias = (const float*)d_in[3];
    const float* attl = (const float*)d_in[4];
    const float* attr = (const float*)d_in[5];
    float* out = (float*)d_out;

    char* ws = (char*)d_ws;
    __bf16* xlS  = (__bf16*)(ws);                               // 4 MB (frag layout)
    float*  alT  = (float*)(ws + (4u << 20));                   // 128 KB
    float*  arT  = (float*)(ws + (4u << 20) + (128u << 10));    // 128 KB
    u64*    abit = (u64*)(ws + (4u << 20) + (256u << 10));      // 2 MB

    kA<<<dim3(GEMM_BLOCKS + PACK_BLOCKS), 256, 0, stream>>>(
        adj, abit, x, W, bias, attl, attr, xlS, alT, arT);
    k3_attn<<<dim3(NH, NN / 64), 512, 0, stream>>>(abit, xlS, alT, arT, out);
}

// Round 11
// 64.619 us; speedup vs baseline: 2.7354x; 1.0927x over previous
//
#include <hip/hip_runtime.h>
#include <hip/hip_bf16.h>

// GATConv on MI355X.
// Pipeline (2 kernels):
//   kA: blocks [0,512): x_l tile GEMM (bf16 MFMA); epilogue writes x_l DIRECTLY
//       in MFMA B-fragment order xlS[h][jw][s][n][lane][8] (lane-contiguous 16B
//       loads in k3), plus per-head alpha_l/alpha_r (alpha_l pre-scaled log2e).
//       blocks [512,4608): pack adj (64MB int32) -> 2MB bitmask, tile-transposed
//       [i>>5][jw][i&31]; 8 rows/wave-iter for memory-level parallelism.
//   k3: block = (head, i-tile 32), 8 waves = 8 j-eighths (R7 shape: best measured).
//       Mask via in-register sign-extend bit-extract on the COMPLEMENTED word:
//       bias_bits = sbfe(~(word>>off), e, 1) & bits(-1000.0f)  -> ~2 VALU/elem
//       (replaces the 3-op and/cmp/cndmask chain; R8 proved select removal
//       = -21pt VALUBusy). bit set -> ~word bit 0 -> bias 0; bit clear -> -1000.
//       P = exp2(fma(al2, ar, bias)) in MFMA A-frag layout; acc += P @ x_l;
//       Z via MFMA ones-B. 2-phase x 3-round LDS tree reduce,
//       out = relu(acc*rcp(Z)).
//   grid.x = 8 heads = 8 XCDs -> per-head xlS L2 locality.

#define NN    4096
#define NF    512
#define NH    8
#define CC    64
#define HC    512   // NH*CC
#define GEMM_BLOCKS 512
#define PACK_BLOCKS 4096

typedef __bf16 bf16x8 __attribute__((ext_vector_type(8)));
typedef __bf16 bf16x4 __attribute__((ext_vector_type(4)));
typedef float  f32x4  __attribute__((ext_vector_type(4)));
typedef unsigned int u32;
typedef unsigned long long u64;

__device__ __forceinline__ float exp2_raw(float x) {
    float r;
    asm("v_exp_f32 %0, %1" : "=v"(r) : "v"(x));
    return r;
}

#if __has_builtin(__builtin_amdgcn_sbfe)
#define SBFE1(x, off) __builtin_amdgcn_sbfe((int)(x), (off), 1)
#else
#define SBFE1(x, off) (((int)((u32)(x) << (31 - (off)))) >> 31)
#endif

// bias from COMPLEMENTED word: bit e of wnot set (edge absent) -> -1000.0f else 0.
__device__ __forceinline__ float mask_bias(u32 wnot, int e) {
    return __uint_as_float(((u32)SBFE1(wnot, e)) & 0xC47A0000u);
}

// ---------------- kA: fused pack + projection GEMM + frag-layout store ----------------
__global__ __launch_bounds__(256) void kA(
    const int* __restrict__ adj, u64* __restrict__ bits,
    const float* __restrict__ X, const float* __restrict__ W,
    const float* __restrict__ bias, const float* __restrict__ attl,
    const float* __restrict__ attr, __bf16* __restrict__ xlS,
    float* __restrict__ alT, float* __restrict__ arT)
{
    const int tid = threadIdx.x;

    if (blockIdx.x >= GEMM_BLOCKS) {
        // ---- pack path: 8 rows per wave-iter (8 loads in flight), bitmask out ----
        const int bid  = blockIdx.x - GEMM_BLOCKS;
        const int lane = tid & 63;
        const int wid  = bid * 4 + (tid >> 6);      // 16384 waves
        for (int u = wid; u < 32768; u += 16384) {  // (4096/8 rowgroups) * 64 jw
            const int i0 = (u >> 6) * 8;
            const int jw = u & 63;
            const int ja = jw * 64 + lane;
            const u64 b0 = __ballot(adj[(i0 + 0) * NN + ja] != 0);
            const u64 b1 = __ballot(adj[(i0 + 1) * NN + ja] != 0);
            const u64 b2 = __ballot(adj[(i0 + 2) * NN + ja] != 0);
            const u64 b3 = __ballot(adj[(i0 + 3) * NN + ja] != 0);
            const u64 b4 = __ballot(adj[(i0 + 4) * NN + ja] != 0);
            const u64 b5 = __ballot(adj[(i0 + 5) * NN + ja] != 0);
            const u64 b6 = __ballot(adj[(i0 + 6) * NN + ja] != 0);
            const u64 b7 = __ballot(adj[(i0 + 7) * NN + ja] != 0);
            if (lane < 8) {
                const int r = lane;
                const u64 wr = (r < 4) ? ((r < 2) ? (r < 1 ? b0 : b1) : (r < 3 ? b2 : b3))
                                       : ((r < 6) ? (r < 5 ? b4 : b5) : (r < 7 ? b6 : b7));
                const int i = i0 + r;
                bits[((i >> 5) * 64 + jw) * 32 + (i & 31)] = wr;
            }
        }
        return;
    }

    // ---- GEMM path: one (64-node, 1-head) tile ----
    __shared__ __bf16 As[64][40];
    __shared__ __bf16 BsT[64][40];
    __shared__ __bf16 T[64][72];

    const int w  = tid >> 6;
    const int l  = tid & 63;
    const int lo = l & 15;
    const int hi = l >> 4;
    const int r0 = (blockIdx.x & 63) * 64;   // node base == jw*64
    const int h  = blockIdx.x >> 6;
    const int c0 = h * CC;
    const int wm = (w >> 1) * 32;
    const int wn = (w & 1) * 32;

    f32x4 acc[2][2];
#pragma unroll
    for (int m = 0; m < 2; ++m)
#pragma unroll
        for (int n = 0; n < 2; ++n) acc[m][n] = (f32x4){0.f, 0.f, 0.f, 0.f};

    const int arow = tid >> 3;
    const int acol = (tid & 7) * 4;
    const int brow = tid >> 4;
    const int bcol = (tid & 15) * 4;

    for (int k0 = 0; k0 < NF; k0 += 32) {
        __syncthreads();
#pragma unroll
        for (int p = 0; p < 2; ++p) {
            int r = arow + p * 32;
            float4 v = *reinterpret_cast<const float4*>(&X[(r0 + r) * NF + k0 + acol]);
            bf16x4 av;
            av[0] = (__bf16)v.x; av[1] = (__bf16)v.y; av[2] = (__bf16)v.z; av[3] = (__bf16)v.w;
            *reinterpret_cast<bf16x4*>(&As[r][acol]) = av;
        }
#pragma unroll
        for (int p = 0; p < 2; ++p) {
            int kk = brow + p * 16;
            float4 v = *reinterpret_cast<const float4*>(&W[(k0 + kk) * HC + c0 + bcol]);
            BsT[bcol + 0][kk] = (__bf16)v.x;
            BsT[bcol + 1][kk] = (__bf16)v.y;
            BsT[bcol + 2][kk] = (__bf16)v.z;
            BsT[bcol + 3][kk] = (__bf16)v.w;
        }
        __syncthreads();

        bf16x8 a[2], b[2];
#pragma unroll
        for (int m = 0; m < 2; ++m)
            a[m] = *reinterpret_cast<const bf16x8*>(&As[wm + m * 16 + lo][hi * 8]);
#pragma unroll
        for (int n = 0; n < 2; ++n)
            b[n] = *reinterpret_cast<const bf16x8*>(&BsT[wn + n * 16 + lo][hi * 8]);
#pragma unroll
        for (int m = 0; m < 2; ++m)
#pragma unroll
            for (int n = 0; n < 2; ++n)
                acc[m][n] = __builtin_amdgcn_mfma_f32_16x16x32_bf16(a[m], b[n], acc[m][n], 0, 0, 0);
    }

    // epilogue: bias + bf16 round into LDS tile T[node-in-tile][channel]
    __syncthreads();
#pragma unroll
    for (int n = 0; n < 2; ++n) {
        const float bv = bias[c0 + wn + n * 16 + lo];
#pragma unroll
        for (int m = 0; m < 2; ++m)
#pragma unroll
            for (int r = 0; r < 4; ++r)
                T[wm + m * 16 + hi * 4 + r][wn + n * 16 + lo] = (__bf16)(acc[m][n][r] + bv);
    }
    __syncthreads();

    // store in k3's B-fragment order: xlS[((h*64+jw)*2+s)*4+n][lane][8]
    {
        const int jw = blockIdx.x & 63;
#pragma unroll
        for (int p = 0; p < 2; ++p) {
            const int z   = tid + p * 256;
            const int s   = z >> 8;
            const int n   = (z >> 6) & 3;
            const int ln  = z & 63;
            const int hi2 = ln >> 4;
            const int lo2 = ln & 15;
            bf16x8 g;
#pragma unroll
            for (int e = 0; e < 8; ++e)
                g[e] = T[s * 32 + hi2 * 8 + e][n * 16 + lo2];
            *reinterpret_cast<bf16x8*>(
                &xlS[(size_t)((((h * 64 + jw) * 2 + s) * 4 + n) * 64 + ln) * 8]) = g;
        }
    }
    // alpha_l (scaled by log2e) / alpha_r for these 64 nodes
    {
        const int row = tid >> 2;
        const int q   = tid & 3;
        float pl = 0.f, pr = 0.f;
#pragma unroll
        for (int c = 0; c < 16; ++c) {
            const int cc = q * 16 + c;
            const float f = (float)T[row][cc];
            pl += f * attl[c0 + cc];
            pr += f * attr[c0 + cc];
        }
        pl += __shfl_xor(pl, 1); pl += __shfl_xor(pl, 2);
        pr += __shfl_xor(pr, 1); pr += __shfl_xor(pr, 2);
        if (q == 0) {
            alT[h * NN + r0 + row] = pl * 1.4426950408889634f;
            arT[h * NN + r0 + row] = pr;
        }
    }
}

// ---------------- k3: fused mask+exp+aggregate+Z+normalize+ReLU ----------------
__global__ __launch_bounds__(512) void k3_attn(
    const u64* __restrict__ bits, const __bf16* __restrict__ xlS,
    const float* __restrict__ alT, const float* __restrict__ arT,
    float* __restrict__ out)
{
    __shared__ float rb[4][64][21];   // [slot][lane][payload+pad] = 21.5 KB

    const int tid = threadIdx.x;
    const int wv  = tid >> 6;        // 8 waves : j-eighths
    const int l   = tid & 63;
    const int lo  = l & 15;
    const int hi  = l >> 4;
    const int h   = blockIdx.x;      // head (== XCD via round-robin dispatch)
    const int i0  = blockIdx.y * 32;
    const int off = hi * 8;          // bit offset within 32-bit mask word

    const float al20 = alT[h * NN + i0 + lo];
    const float al21 = alT[h * NN + i0 + 16 + lo];

    f32x4 acc[2][4];
    f32x4 accz[2];
#pragma unroll
    for (int m = 0; m < 2; ++m) {
        accz[m] = (f32x4){0.f, 0.f, 0.f, 0.f};
#pragma unroll
        for (int n = 0; n < 4; ++n) acc[m][n] = (f32x4){0.f, 0.f, 0.f, 0.f};
    }
    bf16x8 ones;
#pragma unroll
    for (int j = 0; j < 8; ++j) ones[j] = (__bf16)1.0f;

    const float* arp = &arT[h * NN];
    const __bf16* xs = xlS + (size_t)h * (64 * 4096);
    const u64* bT = bits + (size_t)blockIdx.y * 64 * 32;
    const int w0 = wv * 8;

#pragma unroll
    for (int it = 0; it < 8; ++it) {
        const int jw = w0 + it;
        const u64 ab0 = bT[jw * 32 + lo];
        const u64 ab1 = bT[jw * 32 + 16 + lo];
#pragma unroll
        for (int s = 0; s < 2; ++s) {
            const int jj = jw * 64 + s * 32 + hi * 8;
            const f32x4 rv0 = *reinterpret_cast<const f32x4*>(arp + jj);
            const f32x4 rv1 = *reinterpret_cast<const f32x4*>(arp + jj + 4);
            bf16x8 bX[4];
#pragma unroll
            for (int n = 0; n < 4; ++n)
                bX[n] = *reinterpret_cast<const bf16x8*>(
                    &xs[(jw * 2 + s) * 2048 + n * 512 + l * 8]);
#pragma unroll
            for (int m = 0; m < 2; ++m) {
                // 32-bit mask word for this (m, s); shift then COMPLEMENT so
                // sbfe(wnot, e) = 0 when the edge exists (bias 0), -1 when absent.
                const u32 word = (u32)((m ? ab1 : ab0) >> (s * 32));
                const u32 wnot = ~(word >> off);
                const float alm = m ? al21 : al20;
                const float p0 = exp2_raw(__builtin_fmaf(alm, rv0[0], mask_bias(wnot, 0)));
                const float p1 = exp2_raw(__builtin_fmaf(alm, rv0[1], mask_bias(wnot, 1)));
                const float p2 = exp2_raw(__builtin_fmaf(alm, rv0[2], mask_bias(wnot, 2)));
                const float p3 = exp2_raw(__builtin_fmaf(alm, rv0[3], mask_bias(wnot, 3)));
                const float p4 = exp2_raw(__builtin_fmaf(alm, rv1[0], mask_bias(wnot, 4)));
                const float p5 = exp2_raw(__builtin_fmaf(alm, rv1[1], mask_bias(wnot, 5)));
                const float p6 = exp2_raw(__builtin_fmaf(alm, rv1[2], mask_bias(wnot, 6)));
                const float p7 = exp2_raw(__builtin_fmaf(alm, rv1[3], mask_bias(wnot, 7)));
                bf16x8 aP;
                aP[0] = (__bf16)p0; aP[1] = (__bf16)p1; aP[2] = (__bf16)p2; aP[3] = (__bf16)p3;
                aP[4] = (__bf16)p4; aP[5] = (__bf16)p5; aP[6] = (__bf16)p6; aP[7] = (__bf16)p7;
                accz[m] = __builtin_amdgcn_mfma_f32_16x16x32_bf16(aP, ones, accz[m], 0, 0, 0);
#pragma unroll
                for (int n = 0; n < 4; ++n)
                    acc[m][n] = __builtin_amdgcn_mfma_f32_16x16x32_bf16(aP, bX[n], acc[m][n], 0, 0, 0);
            }
        }
    }

    // ---- 2-phase x 3-round LDS tree reduce across 8 waves ----
#pragma unroll
    for (int m = 0; m < 2; ++m) {
        if (wv >= 4) {
#pragma unroll
            for (int n = 0; n < 4; ++n)
#pragma unroll
                for (int r = 0; r < 4; ++r)
                    rb[wv - 4][l][n * 4 + r] = acc[m][n][r];
#pragma unroll
            for (int r = 0; r < 4; ++r)
                rb[wv - 4][l][16 + r] = accz[m][r];
        }
        __syncthreads();
        if (wv < 4) {
#pragma unroll
            for (int n = 0; n < 4; ++n)
#pragma unroll
                for (int r = 0; r < 4; ++r)
                    acc[m][n][r] += rb[wv][l][n * 4 + r];
#pragma unroll
            for (int r = 0; r < 4; ++r)
                accz[m][r] += rb[wv][l][16 + r];
        }
        __syncthreads();
        if (wv >= 2 && wv < 4) {
#pragma unroll
            for (int n = 0; n < 4; ++n)
#pragma unroll
                for (int r = 0; r < 4; ++r)
                    rb[wv - 2][l][n * 4 + r] = acc[m][n][r];
#pragma unroll
            for (int r = 0; r < 4; ++r)
                rb[wv - 2][l][16 + r] = accz[m][r];
        }
        __syncthreads();
        if (wv < 2) {
#pragma unroll
            for (int n = 0; n < 4; ++n)
#pragma unroll
                for (int r = 0; r < 4; ++r)
                    acc[m][n][r] += rb[wv][l][n * 4 + r];
#pragma unroll
            for (int r = 0; r < 4; ++r)
                accz[m][r] += rb[wv][l][16 + r];
        }
        __syncthreads();
        if (wv == 1) {
#pragma unroll
            for (int n = 0; n < 4; ++n)
#pragma unroll
                for (int r = 0; r < 4; ++r)
                    rb[0][l][n * 4 + r] = acc[m][n][r];
#pragma unroll
            for (int r = 0; r < 4; ++r)
                rb[0][l][16 + r] = accz[m][r];
        }
        __syncthreads();
        if (wv == 0) {
#pragma unroll
            for (int r = 0; r < 4; ++r) {
                const float zf = accz[m][r] + rb[0][l][16 + r];
                const float zr = __builtin_amdgcn_rcpf(zf);
                const int row = i0 + m * 16 + hi * 4 + r;
#pragma unroll
                for (int n = 0; n < 4; ++n) {
                    const float o = (acc[m][n][r] + rb[0][l][n * 4 + r]) * zr;
                    out[row * HC + h * CC + n * 16 + lo] = o > 0.f ? o : 0.f;
                }
            }
        }
        if (m == 0) __syncthreads();   // protect buffer reuse for phase 1
    }
}

extern "C" void kernel_launch(void* const* d_in, const int* in_sizes, int n_in,
                              void* d_out, int out_size, void* d_ws, size_t ws_size,
                              hipStream_t stream)
{
    const float* x    = (const float*)d_in[0];
    const int*   adj  = (const int*)d_in[1];
    const float* W    = (const float*)d_in[2];
    const float* bias = (const float*)d_in[3];
    const float* attl = (const float*)d_in[4];
    const float* attr = (const float*)d_in[5];
    float* out = (float*)d_out;

    char* ws = (char*)d_ws;
    __bf16* xlS  = (__bf16*)(ws);                               // 4 MB (frag layout)
    float*  alT  = (float*)(ws + (4u << 20));                   // 128 KB
    float*  arT  = (float*)(ws + (4u << 20) + (128u << 10));    // 128 KB
    u64*    abit = (u64*)(ws + (4u << 20) + (256u << 10));      // 2 MB

    kA<<<dim3(GEMM_BLOCKS + PACK_BLOCKS), 256, 0, stream>>>(
        adj, abit, x, W, bias, attl, attr, xlS, alT, arT);
    k3_attn<<<dim3(NH, NN / 32), 512, 0, stream>>>(abit, xlS, alT, arT, out);
}